// Round 1
// baseline (155.452 us; speedup 1.0000x reference)
//
#include <hip/hip_runtime.h>
#include <hip/hip_bf16.h>

typedef __attribute__((ext_vector_type(8))) short bf16x8;
typedef __attribute__((ext_vector_type(4))) float f32x4;

__device__ __forceinline__ unsigned short f2bf(float f) {
  unsigned int u = __float_as_uint(f);
  u += 0x7FFFu + ((u >> 16) & 1u);   // RTNE
  return (unsigned short)(u >> 16);
}

__host__ __device__ constexpr int prOffset(int l) {
  return (l == 0) ? 0 : (l == 1) ? 3072 : (l == 2) ? 3840 : 4032;
}

// k-th and (k+1)-th order statistics of |row*sc| (N<=32), jax-linear quantile.
template<int N>
__device__ __forceinline__ float row_thr(const float* __restrict__ row, float sc) {
  float v[N];
#pragma unroll
  for (int j = 0; j < N; ++j) v[j] = fabsf(row[j] * sc);
  constexpr float p = 0.4f * (float)(N - 1);   // f32, matches jax index = q*(n-1)
  constexpr int k = (int)p;
  constexpr float frac = p - (float)k;
  float vlo = 0.f, vhi = 0.f;
  for (int i = 0; i < N; ++i) {                // runtime outer: small static code
    const float vi = fabsf(row[i] * sc);
    int clt = 0, ceq = 0;
#pragma unroll
    for (int j = 0; j < N; ++j) {
      clt += (v[j] < vi) ? 1 : 0;
      ceq += (v[j] == vi) ? 1 : 0;
    }
    if (clt <= k && k < clt + ceq) vlo = vi;
    if (clt <= k + 1 && (k + 1) < clt + ceq) vhi = vi;
  }
  return vlo * (1.0f - frac) + vhi * frac;     // jax: low*(1-frac)+high*frac
}

// One block per image. Full wavelet pyramid in LDS, f32 exact order vs jax.
// Writes out[b][n] = wavelet[b][n] + bias[n]  (initializes poisoned d_out).
__global__ __launch_bounds__(256) void wavelet_kernel(
    const float* __restrict__ x,
    const float* __restrict__ bias,
    const float* __restrict__ scl,   // (4,4)
    float* __restrict__ out) {
  __shared__ float cur[4096];
  __shared__ float tmp[4096];
  __shared__ float pr[4096];   // pruned H,V,D all levels + pruned cA3
  const int b = blockIdx.x;
  const int tid = threadIdx.x;
  const float* xi = x + (size_t)b * 4096;

  for (int i = tid; i < 4096; i += 256) cur[i] = xi[i];
  __syncthreads();

  int h = 64;
#pragma unroll
  for (int l = 0; l < 4; ++l) {
    const int half = h >> 1;
    const int hh = half * half;
    // DWT (raw, unscaled) into tmp[s*hh + ...]
    for (int e = tid; e < hh; e += 256) {
      const int i = e / half, j = e - i * half;
      const float a  = cur[(i * 2) * h + j * 2];
      const float bb = cur[(i * 2) * h + j * 2 + 1];
      const float c  = cur[(i * 2 + 1) * h + j * 2];
      const float d  = cur[(i * 2 + 1) * h + j * 2 + 1];
      tmp[e]          = (((a + bb) + c) + d) * 0.5f;
      tmp[hh + e]     = (((a - bb) + c) - d) * 0.5f;
      tmp[2 * hh + e] = (((a + bb) - c) - d) * 0.5f;
      tmp[3 * hh + e] = (((a - bb) - c) + d) * 0.5f;
    }
    __syncthreads();
    // Per-row quantile + prune (store scaled pruned H,V,D; cA only at l==3)
    const int nrows = 4 * half;
    if (tid < nrows) {
      const int s = tid / half, i = tid - s * half;
      const float sc = scl[l * 4 + s];
      const float* row = &tmp[s * hh + i * half];
      float thr;
      if (half == 32)      thr = row_thr<32>(row, sc);
      else if (half == 16) thr = row_thr<16>(row, sc);
      else if (half == 8)  thr = row_thr<8>(row, sc);
      else                 thr = row_thr<4>(row, sc);
      float* dst = nullptr;
      if (s >= 1)          dst = &pr[prOffset(l) + (s - 1) * hh + i * half];
      else if (l == 3)     dst = &pr[4080 + i * 4];
      if (dst) {
        for (int j = 0; j < half; ++j) {
          const float co = row[j] * sc;
          dst[j] = (fabsf(co) > thr) ? co : 0.0f;
        }
      }
    }
    // raw (unscaled, unpruned) cA feeds next level
    for (int e = tid; e < hh; e += 256) cur[e] = tmp[e];
    __syncthreads();
    h = half;
  }

  // Reconstruction: rec = pruned cA3, then idwt up with pruned H,V,D.
#pragma unroll
  for (int l = 3; l >= 0; --l) {
    const int half = 64 >> (l + 1);
    const int hh = half * half;
    const int po = prOffset(l);
    const float* src = (l == 3) ? &pr[4080] : ((l & 1) ? tmp : cur);
    float* dst = (l & 1) ? cur : tmp;
    const int W2 = half * 2;
    for (int e = tid; e < hh; e += 256) {
      const int i = e / half, j = e - i * half;
      const float cA = src[e];
      const float cH = pr[po + 0 * hh + i * half + j];
      const float cV = pr[po + 1 * hh + i * half + j];
      const float cD = pr[po + 2 * hh + i * half + j];
      const float a2 = (((cA + cH) + cV) + cD) * 0.5f;
      const float b2 = (((cA - cH) + cV) - cD) * 0.5f;
      const float c2 = (((cA + cH) - cV) - cD) * 0.5f;
      const float d2 = (((cA - cH) - cV) + cD) * 0.5f;
      dst[(i * 2) * W2 + j * 2]         = a2;
      dst[(i * 2) * W2 + j * 2 + 1]     = b2;
      dst[(i * 2 + 1) * W2 + j * 2]     = c2;
      dst[(i * 2 + 1) * W2 + j * 2 + 1] = d2;
    }
    __syncthreads();
  }
  // l=0 wrote into tmp (64x64)
  float* o = out + (size_t)b * 4096;
  for (int e = tid; e < 4096; e += 256) o[e] = tmp[e] + bias[e];
}

// GEMM: out += x @ W^T.  BM=128(all of M), BN=64, BK=32, split-K=8.
// f32 global loads, in-register cvt to bf16, LDS double-buffer, MFMA 16x16x32.
__global__ __launch_bounds__(256, 2) void gemm_kernel(
    const float* __restrict__ x,
    const float* __restrict__ w,
    float* __restrict__ out) {
  __shared__ __align__(16) unsigned short Asm[2][128][40]; // +8 pad: bank spread
  __shared__ __align__(16) unsigned short Bsm[2][64][40];
  const int tid = threadIdx.x;
  const int nt = blockIdx.x & 63;   // 64 N tiles
  const int ks = blockIdx.x >> 6;   // 8 K splits
  const int n0 = nt * 64;
  const int k0 = ks * 512;
  const int q = tid & 7;            // k-quad (4 floats)
  const int r0 = tid >> 3;          // row 0..31
  const int lane = tid & 63, wid = tid >> 6;
  const int wm = wid >> 1, wn = wid & 1;
  const int fr = lane & 15;
  const int k8 = (lane >> 4) * 8;

  f32x4 acc[4][2];
#pragma unroll
  for (int mi = 0; mi < 4; ++mi)
#pragma unroll
    for (int ni = 0; ni < 2; ++ni)
      acc[mi][ni] = f32x4{0.f, 0.f, 0.f, 0.f};

  float4 ra[4];
  float4 rb[2];
  // prologue: tile 0 -> regs -> LDS buf 0
#pragma unroll
  for (int p = 0; p < 4; ++p)
    ra[p] = *(const float4*)&x[(size_t)(r0 + p * 32) * 4096 + k0 + q * 4];
#pragma unroll
  for (int p = 0; p < 2; ++p)
    rb[p] = *(const float4*)&w[(size_t)(n0 + r0 + p * 32) * 4096 + k0 + q * 4];
#pragma unroll
  for (int p = 0; p < 4; ++p) {
    ushort4 pk = {f2bf(ra[p].x), f2bf(ra[p].y), f2bf(ra[p].z), f2bf(ra[p].w)};
    *(ushort4*)&Asm[0][r0 + p * 32][q * 4] = pk;
  }
#pragma unroll
  for (int p = 0; p < 2; ++p) {
    ushort4 pk = {f2bf(rb[p].x), f2bf(rb[p].y), f2bf(rb[p].z), f2bf(rb[p].w)};
    *(ushort4*)&Bsm[0][r0 + p * 32][q * 4] = pk;
  }
  __syncthreads();

  for (int t = 0; t < 16; ++t) {
    const int cb = t & 1;
    if (t < 15) {  // issue next-tile global loads early (hide under MFMA)
      const int kg = k0 + (t + 1) * 32;
#pragma unroll
      for (int p = 0; p < 4; ++p)
        ra[p] = *(const float4*)&x[(size_t)(r0 + p * 32) * 4096 + kg + q * 4];
#pragma unroll
      for (int p = 0; p < 2; ++p)
        rb[p] = *(const float4*)&w[(size_t)(n0 + r0 + p * 32) * 4096 + kg + q * 4];
    }
    // compute current buffer
    bf16x8 af[4], bg[2];
#pragma unroll
    for (int mi = 0; mi < 4; ++mi)
      af[mi] = *(const bf16x8*)&Asm[cb][wm * 64 + mi * 16 + fr][k8];
#pragma unroll
    for (int ni = 0; ni < 2; ++ni)
      bg[ni] = *(const bf16x8*)&Bsm[cb][wn * 32 + ni * 16 + fr][k8];
#pragma unroll
    for (int mi = 0; mi < 4; ++mi)
#pragma unroll
      for (int ni = 0; ni < 2; ++ni)
        acc[mi][ni] = __builtin_amdgcn_mfma_f32_16x16x32_bf16(
            af[mi], bg[ni], acc[mi][ni], 0, 0, 0);
    if (t < 15) {  // write next tile into other buffer (waits vmcnt implicitly)
#pragma unroll
      for (int p = 0; p < 4; ++p) {
        ushort4 pk = {f2bf(ra[p].x), f2bf(ra[p].y), f2bf(ra[p].z), f2bf(ra[p].w)};
        *(ushort4*)&Asm[cb ^ 1][r0 + p * 32][q * 4] = pk;
      }
#pragma unroll
      for (int p = 0; p < 2; ++p) {
        ushort4 pk = {f2bf(rb[p].x), f2bf(rb[p].y), f2bf(rb[p].z), f2bf(rb[p].w)};
        *(ushort4*)&Bsm[cb ^ 1][r0 + p * 32][q * 4] = pk;
      }
    }
    __syncthreads();
  }

  // epilogue: C/D layout col=lane&15, row=(lane>>4)*4+j   [m89-verified]
  const int rbase = wm * 64 + (lane >> 4) * 4;
  const int cbase = n0 + wn * 32 + fr;
#pragma unroll
  for (int mi = 0; mi < 4; ++mi)
#pragma unroll
    for (int ni = 0; ni < 2; ++ni)
#pragma unroll
      for (int j = 0; j < 4; ++j)
        atomicAdd(&out[(size_t)(rbase + mi * 16 + j) * 4096 + cbase + ni * 16],
                  acc[mi][ni][j]);
}

extern "C" void kernel_launch(void* const* d_in, const int* in_sizes, int n_in,
                              void* d_out, int out_size, void* d_ws, size_t ws_size,
                              hipStream_t stream) {
  const float* x    = (const float*)d_in[0];
  const float* w    = (const float*)d_in[1];
  const float* bias = (const float*)d_in[2];
  const float* scl  = (const float*)d_in[3];
  float* out = (float*)d_out;
  hipLaunchKernelGGL(wavelet_kernel, dim3(128), dim3(256), 0, stream,
                     x, bias, scl, out);
  hipLaunchKernelGGL(gemm_kernel, dim3(512), dim3(256), 0, stream,
                     x, w, out);
}

// Round 3
// 153.487 us; speedup vs baseline: 1.0128x; 1.0128x over previous
//
#include <hip/hip_runtime.h>
#include <hip/hip_bf16.h>

typedef __attribute__((ext_vector_type(8))) short bf16x8;
typedef __attribute__((ext_vector_type(4))) float f32x4;

__device__ __forceinline__ unsigned short f2bf(float f) {
  unsigned int u = __float_as_uint(f);
  u += 0x7FFFu + ((u >> 16) & 1u);   // RTNE
  return (unsigned short)(u >> 16);
}

__device__ __forceinline__ bf16x8 pack8(float4 lo, float4 hi) {
  union { unsigned int u[4]; bf16x8 v; } r;
  asm("v_cvt_pk_bf16_f32 %0, %1, %2" : "=v"(r.u[0]) : "v"(lo.x), "v"(lo.y));
  asm("v_cvt_pk_bf16_f32 %0, %1, %2" : "=v"(r.u[1]) : "v"(lo.z), "v"(lo.w));
  asm("v_cvt_pk_bf16_f32 %0, %1, %2" : "=v"(r.u[2]) : "v"(hi.x), "v"(hi.y));
  asm("v_cvt_pk_bf16_f32 %0, %1, %2" : "=v"(r.u[3]) : "v"(hi.z), "v"(hi.w));
  return r.v;
}

__host__ __device__ constexpr int prOffset(int l) {
  return (l == 0) ? 0 : (l == 1) ? 3072 : (l == 2) ? 3840 : 4032;
}

// ---------------- wavelet: one block per image, element-parallel quantile ---
template<int L>
__device__ __forceinline__ void level_fwd(float* cur, float* tmp, float* ab,
                                          float* pr, float* thrL, float* thrH,
                                          const float* __restrict__ scl, int tid) {
  constexpr int HALF = 32 >> L, LOG2 = 5 - L, HH = HALF * HALF, TOT = 4 * HH;
  constexpr int H = HALF * 2;
  constexpr float P = 0.4f * (float)(HALF - 1);
  constexpr int K = (int)P;
  constexpr float FRAC = P - (float)K;
  const float s0 = scl[4 * L + 0], s1 = scl[4 * L + 1];
  const float s2 = scl[4 * L + 2], s3 = scl[4 * L + 3];
  // DWT (raw, unscaled): cur[(2i,2j)..] -> tmp[s*HH + i*HALF + j]
  for (int e = tid; e < HH; e += 256) {
    const int i = e >> LOG2, j = e & (HALF - 1);
    const float a = cur[(i * 2) * H + j * 2];
    const float b = cur[(i * 2) * H + j * 2 + 1];
    const float c = cur[(i * 2 + 1) * H + j * 2];
    const float d = cur[(i * 2 + 1) * H + j * 2 + 1];
    tmp[e]          = (((a + b) + c) + d) * 0.5f;
    tmp[HH + e]     = (((a - b) + c) - d) * 0.5f;
    tmp[2 * HH + e] = (((a + b) - c) - d) * 0.5f;
    tmp[3 * HH + e] = (((a - b) - c) + d) * 0.5f;
  }
  __syncthreads();
  // scaled |coeff|
  for (int e = tid; e < TOT; e += 256) {
    const int s = e >> (2 * LOG2);
    const float sc = (s < 2) ? (s == 0 ? s0 : s1) : (s == 2 ? s2 : s3);
    ab[e] = fabsf(tmp[e] * sc);
  }
  __syncthreads();
  // counting selection: ranks K and K+1 per row (row = HALF contiguous elems)
  constexpr int CH = (TOT >= 256) ? TOT / 256 : 1;
  {
    const int base = tid * CH;
    if (base < TOT) {
      const int rowbase = base & ~(HALF - 1);
      float v[CH]; int clt[CH], ceq[CH];
#pragma unroll
      for (int c = 0; c < CH; ++c) { v[c] = ab[base + c]; clt[c] = 0; ceq[c] = 0; }
#pragma unroll
      for (int rr = 0; rr < HALF; ++rr) {
        const float a = ab[rowbase + rr];
#pragma unroll
        for (int c = 0; c < CH; ++c) {
          clt[c] += (a < v[c]) ? 1 : 0;
          ceq[c] += (a == v[c]) ? 1 : 0;
        }
      }
      const int row = base >> LOG2;
#pragma unroll
      for (int c = 0; c < CH; ++c) {
        if (clt[c] <= K && K < clt[c] + ceq[c]) thrL[row] = v[c];
        if (clt[c] <= K + 1 && K + 1 < clt[c] + ceq[c]) thrH[row] = v[c];
      }
    }
  }
  __syncthreads();
  // prune + route (scaled H,V,D -> pr; raw cA -> cur; scaled cA at L==3)
  for (int e = tid; e < TOT; e += 256) {
    const int s = e >> (2 * LOG2);
    const int row = e >> LOG2;
    const float sc = (s < 2) ? (s == 0 ? s0 : s1) : (s == 2 ? s2 : s3);
    const float thr = thrL[row] * (1.0f - FRAC) + thrH[row] * FRAC;
    const float co = tmp[e] * sc;
    const float val = (fabsf(co) > thr) ? co : 0.0f;
    if (s >= 1) pr[prOffset(L) + e - HH] = val;
    else {
      if (L == 3) pr[4080 + e] = val;
      cur[e] = tmp[e];
    }
  }
  __syncthreads();
}

__global__ __launch_bounds__(256) void wavelet_kernel(
    const float* __restrict__ x, const float* __restrict__ bias,
    const float* __restrict__ scl, float* __restrict__ out,
    unsigned short* __restrict__ xb, int writeXb) {
  __shared__ float sh[16384];             // 64 KB: cur|tmp|ab|pr
  float* cur = sh;
  float* tmp = sh + 4096;
  float* ab  = sh + 8192;
  float* pr  = sh + 12288;
  float* thrL = cur + 2048;               // cur[HH..H*H) dead after each DWT
  float* thrH = cur + 2176;
  const int b = blockIdx.x, tid = threadIdx.x;
  const float* xi = x + (size_t)b * 4096;

  for (int i = tid; i < 4096; i += 256) {
    const float v = xi[i];
    cur[i] = v;
    if (writeXb) xb[(size_t)b * 4096 + i] = f2bf(v);
  }
  __syncthreads();

  level_fwd<0>(cur, tmp, ab, pr, thrL, thrH, scl, tid);
  level_fwd<1>(cur, tmp, ab, pr, thrL, thrH, scl, tid);
  level_fwd<2>(cur, tmp, ab, pr, thrL, thrH, scl, tid);
  level_fwd<3>(cur, tmp, ab, pr, thrL, thrH, scl, tid);

  // reconstruction (ping-pong cur/tmp; ends in tmp at l=0)
#pragma unroll
  for (int l = 3; l >= 0; --l) {
    const int half = 64 >> (l + 1);
    const int hh = half * half;
    const int po = prOffset(l);
    const float* src = (l == 3) ? &pr[4080] : ((l & 1) ? tmp : cur);
    float* dst = (l & 1) ? cur : tmp;
    const int W2 = half * 2;
    for (int e = tid; e < hh; e += 256) {
      const int i = e / half, j = e - i * half;
      const float cA = src[e];
      const float cH = pr[po + 0 * hh + i * half + j];
      const float cV = pr[po + 1 * hh + i * half + j];
      const float cD = pr[po + 2 * hh + i * half + j];
      const float a2 = (((cA + cH) + cV) + cD) * 0.5f;
      const float b2 = (((cA - cH) + cV) - cD) * 0.5f;
      const float c2 = (((cA + cH) - cV) - cD) * 0.5f;
      const float d2 = (((cA - cH) - cV) + cD) * 0.5f;
      dst[(i * 2) * W2 + j * 2]         = a2;
      dst[(i * 2) * W2 + j * 2 + 1]     = b2;
      dst[(i * 2 + 1) * W2 + j * 2]     = c2;
      dst[(i * 2 + 1) * W2 + j * 2 + 1] = d2;
    }
    __syncthreads();
  }
  float* o = out + (size_t)b * 4096;
  for (int e = tid; e < 4096; e += 256) o[e] = tmp[e] + bias[e];
}

// ---------------- GEMM (fast path): no LDS, no barriers ---------------------
// grid 512 = 64 n-tiles x 8 k-splits; block 256 = 4 waves.
// wave wv: C cols n0+wv*16+fr, C rows 0..127 (mi 0..7). K-chunk 512, 16 steps.
// B (=W[N][K] row-major) loads f32 straight to regs, cvt_pk -> bf16.
// A loads pre-converted bf16 from ws (L2-resident). 4-deep B / 2-deep A pipe.
__global__ __launch_bounds__(256, 2) void gemm_ws(
    const unsigned short* __restrict__ xb, const float* __restrict__ w,
    float* __restrict__ out) {
  const int tid = threadIdx.x, lane = tid & 63, wv = tid >> 6;
  const int fr = lane & 15, k8 = (lane >> 4) * 8;
  const int nt = blockIdx.x & 63, ks = blockIdx.x >> 6;
  const int n0 = nt * 64, k0 = ks * 512;
  const float* wr = w + (size_t)(n0 + wv * 16 + fr) * 4096 + k0 + k8;
  const unsigned short* xr = xb + (size_t)fr * 4096 + k0 + k8;

  f32x4 acc[8];
#pragma unroll
  for (int mi = 0; mi < 8; ++mi) acc[mi] = f32x4{0.f, 0.f, 0.f, 0.f};

  float4 bfr[4][2];
  bf16x8 afr[2][8];
#pragma unroll
  for (int p = 0; p < 4; ++p) {
    bfr[p][0] = *(const float4*)(wr + p * 32);
    bfr[p][1] = *(const float4*)(wr + p * 32 + 4);
  }
#pragma unroll
  for (int p = 0; p < 2; ++p)
#pragma unroll
    for (int mi = 0; mi < 8; ++mi)
      afr[p][mi] = *(const bf16x8*)(xr + mi * 16 * 4096 + p * 32);

#pragma unroll
  for (int t = 0; t < 16; ++t) {
    const bf16x8 bb = pack8(bfr[t & 3][0], bfr[t & 3][1]);
#pragma unroll
    for (int mi = 0; mi < 8; ++mi)
      acc[mi] = __builtin_amdgcn_mfma_f32_16x16x32_bf16(afr[t & 1][mi], bb,
                                                        acc[mi], 0, 0, 0);
    if (t < 12) {
      bfr[t & 3][0] = *(const float4*)(wr + (t + 4) * 32);
      bfr[t & 3][1] = *(const float4*)(wr + (t + 4) * 32 + 4);
    }
    if (t < 14) {
#pragma unroll
      for (int mi = 0; mi < 8; ++mi)
        afr[t & 1][mi] = *(const bf16x8*)(xr + mi * 16 * 4096 + (t + 2) * 32);
    }
  }

  const int rq = (lane >> 4) * 4;
  const int col = n0 + wv * 16 + fr;
#pragma unroll
  for (int mi = 0; mi < 8; ++mi)
#pragma unroll
    for (int j = 0; j < 4; ++j)
      atomicAdd(&out[(size_t)(mi * 16 + rq + j) * 4096 + col], acc[mi][j]);
}

// ---------------- GEMM fallback (round-1, f32->LDS-bf16) --------------------
__global__ __launch_bounds__(256, 2) void gemm_kernel(
    const float* __restrict__ x, const float* __restrict__ w,
    float* __restrict__ out) {
  __shared__ __align__(16) unsigned short Asm[2][128][40];
  __shared__ __align__(16) unsigned short Bsm[2][64][40];
  const int tid = threadIdx.x;
  const int nt = blockIdx.x & 63, ks = blockIdx.x >> 6;
  const int n0 = nt * 64, k0 = ks * 512;
  const int q = tid & 7, r0 = tid >> 3;
  const int lane = tid & 63, wid = tid >> 6;
  const int wm = wid >> 1, wn = wid & 1;
  const int fr = lane & 15, k8 = (lane >> 4) * 8;

  f32x4 acc[4][2];
#pragma unroll
  for (int mi = 0; mi < 4; ++mi)
#pragma unroll
    for (int ni = 0; ni < 2; ++ni) acc[mi][ni] = f32x4{0.f, 0.f, 0.f, 0.f};

  float4 ra[4]; float4 rb[2];
#pragma unroll
  for (int p = 0; p < 4; ++p)
    ra[p] = *(const float4*)&x[(size_t)(r0 + p * 32) * 4096 + k0 + q * 4];
#pragma unroll
  for (int p = 0; p < 2; ++p)
    rb[p] = *(const float4*)&w[(size_t)(n0 + r0 + p * 32) * 4096 + k0 + q * 4];
#pragma unroll
  for (int p = 0; p < 4; ++p) {
    ushort4 pk = {f2bf(ra[p].x), f2bf(ra[p].y), f2bf(ra[p].z), f2bf(ra[p].w)};
    *(ushort4*)&Asm[0][r0 + p * 32][q * 4] = pk;
  }
#pragma unroll
  for (int p = 0; p < 2; ++p) {
    ushort4 pk = {f2bf(rb[p].x), f2bf(rb[p].y), f2bf(rb[p].z), f2bf(rb[p].w)};
    *(ushort4*)&Bsm[0][r0 + p * 32][q * 4] = pk;
  }
  __syncthreads();

  for (int t = 0; t < 16; ++t) {
    const int cb = t & 1;
    if (t < 15) {
      const int kg = k0 + (t + 1) * 32;
#pragma unroll
      for (int p = 0; p < 4; ++p)
        ra[p] = *(const float4*)&x[(size_t)(r0 + p * 32) * 4096 + kg + q * 4];
#pragma unroll
      for (int p = 0; p < 2; ++p)
        rb[p] = *(const float4*)&w[(size_t)(n0 + r0 + p * 32) * 4096 + kg + q * 4];
    }
    bf16x8 af[4], bg[2];
#pragma unroll
    for (int mi = 0; mi < 4; ++mi)
      af[mi] = *(const bf16x8*)&Asm[cb][wm * 64 + mi * 16 + fr][k8];
#pragma unroll
    for (int ni = 0; ni < 2; ++ni)
      bg[ni] = *(const bf16x8*)&Bsm[cb][wn * 32 + ni * 16 + fr][k8];
#pragma unroll
    for (int mi = 0; mi < 4; ++mi)
#pragma unroll
      for (int ni = 0; ni < 2; ++ni)
        acc[mi][ni] = __builtin_amdgcn_mfma_f32_16x16x32_bf16(af[mi], bg[ni],
                                                              acc[mi][ni], 0, 0, 0);
    if (t < 15) {
#pragma unroll
      for (int p = 0; p < 4; ++p) {
        ushort4 pk = {f2bf(ra[p].x), f2bf(ra[p].y), f2bf(ra[p].z), f2bf(ra[p].w)};
        *(ushort4*)&Asm[cb ^ 1][r0 + p * 32][q * 4] = pk;
      }
#pragma unroll
      for (int p = 0; p < 2; ++p) {
        ushort4 pk = {f2bf(rb[p].x), f2bf(rb[p].y), f2bf(rb[p].z), f2bf(rb[p].w)};
        *(ushort4*)&Bsm[cb ^ 1][r0 + p * 32][q * 4] = pk;
      }
    }
    __syncthreads();
  }

  const int rbase = wm * 64 + (lane >> 4) * 4;
  const int cbase = n0 + wn * 32 + fr;
#pragma unroll
  for (int mi = 0; mi < 4; ++mi)
#pragma unroll
    for (int ni = 0; ni < 2; ++ni)
#pragma unroll
      for (int j = 0; j < 4; ++j)
        atomicAdd(&out[(size_t)(rbase + mi * 16 + j) * 4096 + cbase + ni * 16],
                  acc[mi][ni][j]);
}

extern "C" void kernel_launch(void* const* d_in, const int* in_sizes, int n_in,
                              void* d_out, int out_size, void* d_ws, size_t ws_size,
                              hipStream_t stream) {
  const float* x    = (const float*)d_in[0];
  const float* w    = (const float*)d_in[1];
  const float* bias = (const float*)d_in[2];
  const float* scl  = (const float*)d_in[3];
  float* out = (float*)d_out;
  const bool useWs = ws_size >= (size_t)128 * 4096 * 2;
  unsigned short* xbp = (unsigned short*)d_ws;
  hipLaunchKernelGGL(wavelet_kernel, dim3(128), dim3(256), 0, stream,
                     x, bias, scl, out, xbp, useWs ? 1 : 0);
  if (useWs)
    hipLaunchKernelGGL(gemm_ws, dim3(512), dim3(256), 0, stream, xbp, w, out);
  else
    hipLaunchKernelGGL(gemm_kernel, dim3(512), dim3(256), 0, stream, x, w, out);
}

// Round 4
// 135.607 us; speedup vs baseline: 1.1463x; 1.1318x over previous
//
#include <hip/hip_runtime.h>
#include <hip/hip_bf16.h>

typedef __attribute__((ext_vector_type(8))) short bf16x8;
typedef __attribute__((ext_vector_type(4))) float f32x4;

__device__ __forceinline__ unsigned short f2bf(float f) {
  unsigned int u = __float_as_uint(f);
  u += 0x7FFFu + ((u >> 16) & 1u);   // RTNE
  return (unsigned short)(u >> 16);
}

__device__ __forceinline__ bf16x8 pack8(float4 lo, float4 hi) {
  union { unsigned int u[4]; bf16x8 v; } r;
  asm("v_cvt_pk_bf16_f32 %0, %1, %2" : "=v"(r.u[0]) : "v"(lo.x), "v"(lo.y));
  asm("v_cvt_pk_bf16_f32 %0, %1, %2" : "=v"(r.u[1]) : "v"(lo.z), "v"(lo.w));
  asm("v_cvt_pk_bf16_f32 %0, %1, %2" : "=v"(r.u[2]) : "v"(hi.x), "v"(hi.y));
  asm("v_cvt_pk_bf16_f32 %0, %1, %2" : "=v"(r.u[3]) : "v"(hi.z), "v"(hi.w));
  return r.v;
}

__device__ __forceinline__ void gload16(const void* g, void* l) {
  __builtin_amdgcn_global_load_lds(
      (const __attribute__((address_space(1))) void*)g,
      (__attribute__((address_space(3))) void*)l, 16, 0, 0);
}

__host__ __device__ constexpr int prOffset(int l) {
  return (l == 0) ? 0 : (l == 1) ? 3072 : (l == 2) ? 3840 : 4032;
}

// ---------------- wavelet: one block/image, 512 threads ---------------------
template<int L>
__device__ __forceinline__ void level_fwd(float* cur, float* tmp, float* ab,
                                          float* pr, float* thrL, float* thrH,
                                          const float* __restrict__ scl, int tid) {
  constexpr int HALF = 32 >> L, LOG2 = 5 - L, HH = HALF * HALF, TOT = 4 * HH;
  constexpr int H = HALF * 2;
  constexpr float P = 0.4f * (float)(HALF - 1);
  constexpr int K = (int)P;
  constexpr float FRAC = P - (float)K;
  const float s0 = scl[4 * L + 0], s1 = scl[4 * L + 1];
  const float s2 = scl[4 * L + 2], s3 = scl[4 * L + 3];
  // DWT (raw, unscaled) + fused scaled-abs
  for (int e = tid; e < HH; e += 512) {
    const int i = e >> LOG2, j = e & (HALF - 1);
    const float a = cur[(i * 2) * H + j * 2];
    const float b = cur[(i * 2) * H + j * 2 + 1];
    const float c = cur[(i * 2 + 1) * H + j * 2];
    const float d = cur[(i * 2 + 1) * H + j * 2 + 1];
    const float vA = (((a + b) + c) + d) * 0.5f;
    const float vH = (((a - b) + c) - d) * 0.5f;
    const float vV = (((a + b) - c) - d) * 0.5f;
    const float vD = (((a - b) - c) + d) * 0.5f;
    tmp[e]          = vA;  ab[e]          = fabsf(vA * s0);
    tmp[HH + e]     = vH;  ab[HH + e]     = fabsf(vH * s1);
    tmp[2 * HH + e] = vV;  ab[2 * HH + e] = fabsf(vV * s2);
    tmp[3 * HH + e] = vD;  ab[3 * HH + e] = fabsf(vD * s3);
  }
  __syncthreads();
  // counting selection: ranks K and K+1 per row (row = HALF contiguous elems)
  constexpr int CH = (TOT >= 512) ? TOT / 512 : 1;
  {
    const int base = tid * CH;
    if (base < TOT) {
      const int rowbase = base & ~(HALF - 1);
      float v[CH]; int clt[CH], ceq[CH];
#pragma unroll
      for (int c = 0; c < CH; ++c) { v[c] = ab[base + c]; clt[c] = 0; ceq[c] = 0; }
#pragma unroll
      for (int rr = 0; rr < HALF; ++rr) {
        const float a = ab[rowbase + rr];
#pragma unroll
        for (int c = 0; c < CH; ++c) {
          clt[c] += (a < v[c]) ? 1 : 0;
          ceq[c] += (a == v[c]) ? 1 : 0;
        }
      }
      const int row = base >> LOG2;
#pragma unroll
      for (int c = 0; c < CH; ++c) {
        if (clt[c] <= K && K < clt[c] + ceq[c]) thrL[row] = v[c];
        if (clt[c] <= K + 1 && K + 1 < clt[c] + ceq[c]) thrH[row] = v[c];
      }
    }
  }
  __syncthreads();
  // prune + route (scaled H,V,D -> pr; raw cA -> cur; scaled cA at L==3)
  for (int e = tid; e < TOT; e += 512) {
    const int s = e >> (2 * LOG2);
    const int row = e >> LOG2;
    const float sc = (s < 2) ? (s == 0 ? s0 : s1) : (s == 2 ? s2 : s3);
    const float thr = thrL[row] * (1.0f - FRAC) + thrH[row] * FRAC;
    const float co = tmp[e] * sc;
    const float val = (fabsf(co) > thr) ? co : 0.0f;
    if (s >= 1) pr[prOffset(L) + e - HH] = val;
    else {
      if (L == 3) pr[4080 + e] = val;
      cur[e] = tmp[e];
    }
  }
  __syncthreads();
}

__global__ __launch_bounds__(512) void wavelet_kernel(
    const float* __restrict__ x, const float* __restrict__ bias,
    const float* __restrict__ scl, float* __restrict__ out,
    unsigned short* __restrict__ xb, int writeXb) {
  __shared__ float sh[16384];             // 64 KB: cur|tmp|ab|pr
  float* cur = sh;
  float* tmp = sh + 4096;
  float* ab  = sh + 8192;
  float* pr  = sh + 12288;
  float* thrL = cur + 2048;               // dead region of cur during quantile
  float* thrH = cur + 2176;
  const int b = blockIdx.x, tid = threadIdx.x;
  const float* xi = x + (size_t)b * 4096;

  for (int i = tid; i < 1024; i += 512) {
    const float4 v = ((const float4*)xi)[i];
    *(float4*)&cur[i * 4] = v;
    if (writeXb) {
      ushort4 pk = {f2bf(v.x), f2bf(v.y), f2bf(v.z), f2bf(v.w)};
      *(ushort4*)&xb[(size_t)b * 4096 + i * 4] = pk;
    }
  }
  __syncthreads();

  level_fwd<0>(cur, tmp, ab, pr, thrL, thrH, scl, tid);
  level_fwd<1>(cur, tmp, ab, pr, thrL, thrH, scl, tid);
  level_fwd<2>(cur, tmp, ab, pr, thrL, thrH, scl, tid);
  level_fwd<3>(cur, tmp, ab, pr, thrL, thrH, scl, tid);

  // reconstruction (ping-pong cur/tmp; ends in tmp at l=0)
#pragma unroll
  for (int l = 3; l >= 0; --l) {
    const int half = 64 >> (l + 1);
    const int hh = half * half;
    const int po = prOffset(l);
    const float* src = (l == 3) ? &pr[4080] : ((l & 1) ? tmp : cur);
    float* dst = (l & 1) ? cur : tmp;
    const int W2 = half * 2;
    for (int e = tid; e < hh; e += 512) {
      const int i = e / half, j = e - i * half;
      const float cA = src[e];
      const float cH = pr[po + 0 * hh + i * half + j];
      const float cV = pr[po + 1 * hh + i * half + j];
      const float cD = pr[po + 2 * hh + i * half + j];
      const float a2 = (((cA + cH) + cV) + cD) * 0.5f;
      const float b2 = (((cA - cH) + cV) - cD) * 0.5f;
      const float c2 = (((cA + cH) - cV) - cD) * 0.5f;
      const float d2 = (((cA - cH) - cV) + cD) * 0.5f;
      dst[(i * 2) * W2 + j * 2]         = a2;
      dst[(i * 2) * W2 + j * 2 + 1]     = b2;
      dst[(i * 2 + 1) * W2 + j * 2]     = c2;
      dst[(i * 2 + 1) * W2 + j * 2 + 1] = d2;
    }
    __syncthreads();
  }
  float* o = out + (size_t)b * 4096;
  const float4* t4 = (const float4*)tmp;
  const float4* b4 = (const float4*)bias;
  for (int i = tid; i < 1024; i += 512) {
    float4 t = t4[i], bb = b4[i];
    float4 r = {t.x + bb.x, t.y + bb.y, t.z + bb.z, t.w + bb.w};
    ((float4*)o)[i] = r;
  }
}

// ---------------- GEMM v4: global_load_lds 2-phase, split-K=16 --------------
// grid 1024 = 64 n-tiles x 16 k-splits; block 256 = 4 waves.
// A: bf16 from ws [128][BK=32] tile (8KB); B: f32 from W [64][32] tile (8KB).
// LDS linear for gload_lds; conflict-free via inverse-swizzled GLOBAL src
// (rule 21/m173): A slot' = kq ^ ((r>>1)&3), B slot' = c ^ (r&7).
__global__ __launch_bounds__(256, 4) void gemm_v4(
    const unsigned short* __restrict__ xb, const float* __restrict__ w,
    float* __restrict__ out) {
  __shared__ __align__(16) unsigned short A_lds[2][128 * 32];  // 8KB each
  __shared__ __align__(16) float B_lds[2][64 * 32];            // 8KB each
  const int tid = threadIdx.x, lane = tid & 63, wv = tid >> 6;
  const int fr = lane & 15, kq = lane >> 4;
  const int nt = blockIdx.x & 63, ks = blockIdx.x >> 6;
  const int n0 = nt * 64, k0 = ks * 256;

  // staging global sources (inverse swizzle), fixed per thread; step adds 32 elems
  const int sA0 = tid, sA1 = 256 + tid;
  const int rA0 = sA0 >> 2, cA0 = (sA0 & 3) ^ ((rA0 >> 1) & 3);
  const int rA1 = sA1 >> 2, cA1 = (sA1 & 3) ^ ((rA1 >> 1) & 3);
  const unsigned short* aSrc0 = xb + (size_t)rA0 * 4096 + k0 + cA0 * 8;
  const unsigned short* aSrc1 = xb + (size_t)rA1 * 4096 + k0 + cA1 * 8;
  const int rB0 = sA0 >> 3, cB0 = (sA0 & 7) ^ (rB0 & 7);
  const int rB1 = sA1 >> 3, cB1 = (sA1 & 7) ^ (rB1 & 7);
  const float* bSrc0 = w + (size_t)(n0 + rB0) * 4096 + k0 + cB0 * 4;
  const float* bSrc1 = w + (size_t)(n0 + rB1) * 4096 + k0 + cB1 * 4;

  f32x4 acc[8];
#pragma unroll
  for (int mi = 0; mi < 8; ++mi) acc[mi] = f32x4{0.f, 0.f, 0.f, 0.f};

  // read-side swizzled offsets (constant over steps)
  const int aslot = kq ^ ((fr >> 1) & 3);               // A: (mi*16+fr)>>1 &3 == (fr>>1)&3
  const int R2 = wv * 16 + fr;
  const int bo0 = R2 * 128 + (((kq * 2 + 0) ^ (R2 & 7)) * 16);
  const int bo1 = R2 * 128 + (((kq * 2 + 1) ^ (R2 & 7)) * 16);

  auto STAGE = [&](int buf, int t) {
    gload16(aSrc0 + t * 32, (char*)&A_lds[buf][0] + tid * 16);
    gload16(aSrc1 + t * 32, (char*)&A_lds[buf][0] + (256 + tid) * 16);
    gload16(bSrc0 + t * 32, (char*)&B_lds[buf][0] + tid * 16);
    gload16(bSrc1 + t * 32, (char*)&B_lds[buf][0] + (256 + tid) * 16);
  };

  STAGE(0, 0);
  __syncthreads();
  int cur = 0;
#pragma unroll
  for (int t = 0; t < 8; ++t) {
    if (t < 7) STAGE(cur ^ 1, t + 1);
    const char* Ab = (const char*)&A_lds[cur][0];
    const char* Bb = (const char*)&B_lds[cur][0];
    const float4 b0 = *(const float4*)(Bb + bo0);
    const float4 b1 = *(const float4*)(Bb + bo1);
    const bf16x8 bb = pack8(b0, b1);
#pragma unroll
    for (int mi = 0; mi < 8; ++mi) {
      const bf16x8 af = *(const bf16x8*)(Ab + (mi * 16 + fr) * 64 + aslot * 16);
      acc[mi] = __builtin_amdgcn_mfma_f32_16x16x32_bf16(af, bb, acc[mi], 0, 0, 0);
    }
    __syncthreads();
    cur ^= 1;
  }

  // C/D layout: col=lane&15, row=(lane>>4)*4+j  [m89-verified, matches r1/r3]
  const int col = n0 + wv * 16 + fr;
  const int rq = kq * 4;
#pragma unroll
  for (int mi = 0; mi < 8; ++mi)
#pragma unroll
    for (int j = 0; j < 4; ++j)
      atomicAdd(&out[(size_t)(mi * 16 + rq + j) * 4096 + col], acc[mi][j]);
}

// ---------------- GEMM fallback (round-1, f32->LDS-bf16) --------------------
__global__ __launch_bounds__(256, 2) void gemm_kernel(
    const float* __restrict__ x, const float* __restrict__ w,
    float* __restrict__ out) {
  __shared__ __align__(16) unsigned short Asm[2][128][40];
  __shared__ __align__(16) unsigned short Bsm[2][64][40];
  const int tid = threadIdx.x;
  const int nt = blockIdx.x & 63, ks = blockIdx.x >> 6;
  const int n0 = nt * 64, k0 = ks * 512;
  const int q = tid & 7, r0 = tid >> 3;
  const int lane = tid & 63, wid = tid >> 6;
  const int wm = wid >> 1, wn = wid & 1;
  const int fr = lane & 15, k8 = (lane >> 4) * 8;

  f32x4 acc[4][2];
#pragma unroll
  for (int mi = 0; mi < 4; ++mi)
#pragma unroll
    for (int ni = 0; ni < 2; ++ni) acc[mi][ni] = f32x4{0.f, 0.f, 0.f, 0.f};

  float4 ra[4]; float4 rb[2];
#pragma unroll
  for (int p = 0; p < 4; ++p)
    ra[p] = *(const float4*)&x[(size_t)(r0 + p * 32) * 4096 + k0 + q * 4];
#pragma unroll
  for (int p = 0; p < 2; ++p)
    rb[p] = *(const float4*)&w[(size_t)(n0 + r0 + p * 32) * 4096 + k0 + q * 4];
#pragma unroll
  for (int p = 0; p < 4; ++p) {
    ushort4 pk = {f2bf(ra[p].x), f2bf(ra[p].y), f2bf(ra[p].z), f2bf(ra[p].w)};
    *(ushort4*)&Asm[0][r0 + p * 32][q * 4] = pk;
  }
#pragma unroll
  for (int p = 0; p < 2; ++p) {
    ushort4 pk = {f2bf(rb[p].x), f2bf(rb[p].y), f2bf(rb[p].z), f2bf(rb[p].w)};
    *(ushort4*)&Bsm[0][r0 + p * 32][q * 4] = pk;
  }
  __syncthreads();

  for (int t = 0; t < 16; ++t) {
    const int cb = t & 1;
    if (t < 15) {
      const int kg = k0 + (t + 1) * 32;
#pragma unroll
      for (int p = 0; p < 4; ++p)
        ra[p] = *(const float4*)&x[(size_t)(r0 + p * 32) * 4096 + kg + q * 4];
#pragma unroll
      for (int p = 0; p < 2; ++p)
        rb[p] = *(const float4*)&w[(size_t)(n0 + r0 + p * 32) * 4096 + kg + q * 4];
    }
    bf16x8 af[4], bg[2];
#pragma unroll
    for (int mi = 0; mi < 4; ++mi)
      af[mi] = *(const bf16x8*)&Asm[cb][wm * 64 + mi * 16 + fr][k8];
#pragma unroll
    for (int ni = 0; ni < 2; ++ni)
      bg[ni] = *(const bf16x8*)&Bsm[cb][wn * 32 + ni * 16 + fr][k8];
#pragma unroll
    for (int mi = 0; mi < 4; ++mi)
#pragma unroll
      for (int ni = 0; ni < 2; ++ni)
        acc[mi][ni] = __builtin_amdgcn_mfma_f32_16x16x32_bf16(af[mi], bg[ni],
                                                              acc[mi][ni], 0, 0, 0);
    if (t < 15) {
#pragma unroll
      for (int p = 0; p < 4; ++p) {
        ushort4 pk = {f2bf(ra[p].x), f2bf(ra[p].y), f2bf(ra[p].z), f2bf(ra[p].w)};
        *(ushort4*)&Asm[cb ^ 1][r0 + p * 32][q * 4] = pk;
      }
#pragma unroll
      for (int p = 0; p < 2; ++p) {
        ushort4 pk = {f2bf(rb[p].x), f2bf(rb[p].y), f2bf(rb[p].z), f2bf(rb[p].w)};
        *(ushort4*)&Bsm[cb ^ 1][r0 + p * 32][q * 4] = pk;
      }
    }
    __syncthreads();
  }

  const int rbase = wm * 64 + (lane >> 4) * 4;
  const int cbase = n0 + wn * 32 + fr;
#pragma unroll
  for (int mi = 0; mi < 4; ++mi)
#pragma unroll
    for (int ni = 0; ni < 2; ++ni)
#pragma unroll
      for (int j = 0; j < 4; ++j)
        atomicAdd(&out[(size_t)(rbase + mi * 16 + j) * 4096 + cbase + ni * 16],
                  acc[mi][ni][j]);
}

extern "C" void kernel_launch(void* const* d_in, const int* in_sizes, int n_in,
                              void* d_out, int out_size, void* d_ws, size_t ws_size,
                              hipStream_t stream) {
  const float* x    = (const float*)d_in[0];
  const float* w    = (const float*)d_in[1];
  const float* bias = (const float*)d_in[2];
  const float* scl  = (const float*)d_in[3];
  float* out = (float*)d_out;
  const bool useWs = ws_size >= (size_t)128 * 4096 * 2;
  unsigned short* xbp = (unsigned short*)d_ws;
  hipLaunchKernelGGL(wavelet_kernel, dim3(128), dim3(512), 0, stream,
                     x, bias, scl, out, xbp, useWs ? 1 : 0);
  if (useWs)
    hipLaunchKernelGGL(gemm_v4, dim3(1024), dim3(256), 0, stream, xbp, w, out);
  else
    hipLaunchKernelGGL(gemm_kernel, dim3(512), dim3(256), 0, stream, x, w, out);
}

// Round 5
// 127.759 us; speedup vs baseline: 1.2168x; 1.0614x over previous
//
#include <hip/hip_runtime.h>
#include <hip/hip_bf16.h>

typedef __attribute__((ext_vector_type(8))) short bf16x8;
typedef __attribute__((ext_vector_type(4))) float f32x4;

__device__ __forceinline__ unsigned short f2bf(float f) {
  unsigned int u = __float_as_uint(f);
  u += 0x7FFFu + ((u >> 16) & 1u);   // RTNE
  return (unsigned short)(u >> 16);
}

__device__ __forceinline__ bf16x8 pack8(float4 lo, float4 hi) {
  union { unsigned int u[4]; bf16x8 v; } r;
  asm("v_cvt_pk_bf16_f32 %0, %1, %2" : "=v"(r.u[0]) : "v"(lo.x), "v"(lo.y));
  asm("v_cvt_pk_bf16_f32 %0, %1, %2" : "=v"(r.u[1]) : "v"(lo.z), "v"(lo.w));
  asm("v_cvt_pk_bf16_f32 %0, %1, %2" : "=v"(r.u[2]) : "v"(hi.x), "v"(hi.y));
  asm("v_cvt_pk_bf16_f32 %0, %1, %2" : "=v"(r.u[3]) : "v"(hi.z), "v"(hi.w));
  return r.v;
}

__device__ __forceinline__ void gload16(const void* g, void* l) {
  __builtin_amdgcn_global_load_lds(
      (const __attribute__((address_space(1))) void*)g,
      (__attribute__((address_space(3))) void*)l, 16, 0, 0);
}

__host__ __device__ constexpr int prOffset(int l) {
  return (l == 0) ? 0 : (l == 1) ? 3072 : (l == 2) ? 3840 : 4032;
}

// ---------------- x -> bf16 (ws) ------------------------------------------
__global__ __launch_bounds__(256) void cvt_x(const float* __restrict__ x,
                                             unsigned short* __restrict__ xb) {
  const int i = blockIdx.x * 256 + threadIdx.x;          // 131072 float4s
  const float4 v = ((const float4*)x)[i];
  ushort4 pk = {f2bf(v.x), f2bf(v.y), f2bf(v.z), f2bf(v.w)};
  ((ushort4*)xb)[i] = pk;
}

// ---------------- wavelet: one block/image, 512 threads ---------------------
template<int L>
__device__ __forceinline__ void level_fwd(float* cur, float* tmp, float* ab,
                                          float* pr, float* thrL, float* thrH,
                                          const float* __restrict__ scl, int tid) {
  constexpr int HALF = 32 >> L, LOG2 = 5 - L, HH = HALF * HALF, TOT = 4 * HH;
  constexpr int H = HALF * 2;
  constexpr float P = 0.4f * (float)(HALF - 1);
  constexpr int K = (int)P;
  constexpr float FRAC = P - (float)K;
  const float s0 = scl[4 * L + 0], s1 = scl[4 * L + 1];
  const float s2 = scl[4 * L + 2], s3 = scl[4 * L + 3];
  for (int e = tid; e < HH; e += 512) {
    const int i = e >> LOG2, j = e & (HALF - 1);
    const float a = cur[(i * 2) * H + j * 2];
    const float b = cur[(i * 2) * H + j * 2 + 1];
    const float c = cur[(i * 2 + 1) * H + j * 2];
    const float d = cur[(i * 2 + 1) * H + j * 2 + 1];
    const float vA = (((a + b) + c) + d) * 0.5f;
    const float vH = (((a - b) + c) - d) * 0.5f;
    const float vV = (((a + b) - c) - d) * 0.5f;
    const float vD = (((a - b) - c) + d) * 0.5f;
    tmp[e]          = vA;  ab[e]          = fabsf(vA * s0);
    tmp[HH + e]     = vH;  ab[HH + e]     = fabsf(vH * s1);
    tmp[2 * HH + e] = vV;  ab[2 * HH + e] = fabsf(vV * s2);
    tmp[3 * HH + e] = vD;  ab[3 * HH + e] = fabsf(vD * s3);
  }
  __syncthreads();
  constexpr int CH = (TOT >= 512) ? TOT / 512 : 1;
  {
    const int base = tid * CH;
    if (base < TOT) {
      const int rowbase = base & ~(HALF - 1);
      float v[CH]; int clt[CH], ceq[CH];
#pragma unroll
      for (int c = 0; c < CH; ++c) { v[c] = ab[base + c]; clt[c] = 0; ceq[c] = 0; }
#pragma unroll
      for (int rr = 0; rr < HALF; ++rr) {
        const float a = ab[rowbase + rr];
#pragma unroll
        for (int c = 0; c < CH; ++c) {
          clt[c] += (a < v[c]) ? 1 : 0;
          ceq[c] += (a == v[c]) ? 1 : 0;
        }
      }
      const int row = base >> LOG2;
#pragma unroll
      for (int c = 0; c < CH; ++c) {
        if (clt[c] <= K && K < clt[c] + ceq[c]) thrL[row] = v[c];
        if (clt[c] <= K + 1 && K + 1 < clt[c] + ceq[c]) thrH[row] = v[c];
      }
    }
  }
  __syncthreads();
  for (int e = tid; e < TOT; e += 512) {
    const int s = e >> (2 * LOG2);
    const int row = e >> LOG2;
    const float sc = (s < 2) ? (s == 0 ? s0 : s1) : (s == 2 ? s2 : s3);
    const float thr = thrL[row] * (1.0f - FRAC) + thrH[row] * FRAC;
    const float co = tmp[e] * sc;
    const float val = (fabsf(co) > thr) ? co : 0.0f;
    if (s >= 1) pr[prOffset(L) + e - HH] = val;
    else {
      if (L == 3) pr[4080 + e] = val;
      cur[e] = tmp[e];
    }
  }
  __syncthreads();
}

__global__ __launch_bounds__(512) void wavelet_kernel(
    const float* __restrict__ x, const float* __restrict__ bias,
    const float* __restrict__ scl, float* __restrict__ out,
    unsigned short* __restrict__ xb, const float* __restrict__ partials,
    int writeXb, int addPartials) {
  __shared__ float sh[16384];             // 64 KB: cur|tmp|ab|pr
  float* cur = sh;
  float* tmp = sh + 4096;
  float* ab  = sh + 8192;
  float* pr  = sh + 12288;
  float* thrL = cur + 2048;
  float* thrH = cur + 2176;
  const int b = blockIdx.x, tid = threadIdx.x;
  const float* xi = x + (size_t)b * 4096;

  for (int i = tid; i < 1024; i += 512) {
    const float4 v = ((const float4*)xi)[i];
    *(float4*)&cur[i * 4] = v;
    if (writeXb) {
      ushort4 pk = {f2bf(v.x), f2bf(v.y), f2bf(v.z), f2bf(v.w)};
      *(ushort4*)&xb[(size_t)b * 4096 + i * 4] = pk;
    }
  }
  __syncthreads();

  level_fwd<0>(cur, tmp, ab, pr, thrL, thrH, scl, tid);
  level_fwd<1>(cur, tmp, ab, pr, thrL, thrH, scl, tid);
  level_fwd<2>(cur, tmp, ab, pr, thrL, thrH, scl, tid);
  level_fwd<3>(cur, tmp, ab, pr, thrL, thrH, scl, tid);

#pragma unroll
  for (int l = 3; l >= 0; --l) {
    const int half = 64 >> (l + 1);
    const int hh = half * half;
    const int po = prOffset(l);
    const float* src = (l == 3) ? &pr[4080] : ((l & 1) ? tmp : cur);
    float* dst = (l & 1) ? cur : tmp;
    const int W2 = half * 2;
    for (int e = tid; e < hh; e += 512) {
      const int i = e / half, j = e - i * half;
      const float cA = src[e];
      const float cH = pr[po + 0 * hh + i * half + j];
      const float cV = pr[po + 1 * hh + i * half + j];
      const float cD = pr[po + 2 * hh + i * half + j];
      const float a2 = (((cA + cH) + cV) + cD) * 0.5f;
      const float b2 = (((cA - cH) + cV) - cD) * 0.5f;
      const float c2 = (((cA + cH) - cV) - cD) * 0.5f;
      const float d2 = (((cA - cH) - cV) + cD) * 0.5f;
      dst[(i * 2) * W2 + j * 2]         = a2;
      dst[(i * 2) * W2 + j * 2 + 1]     = b2;
      dst[(i * 2 + 1) * W2 + j * 2]     = c2;
      dst[(i * 2 + 1) * W2 + j * 2 + 1] = d2;
    }
    __syncthreads();
  }
  // epilogue: out = wavelet + bias (+ sum of 8 split-K partials)
  float* o = out + (size_t)b * 4096;
  const float4* t4 = (const float4*)tmp;
  const float4* b4 = (const float4*)bias;
  for (int i = tid; i < 1024; i += 512) {
    float4 t = t4[i], bb = b4[i];
    float4 s = {t.x + bb.x, t.y + bb.y, t.z + bb.z, t.w + bb.w};
    if (addPartials) {
#pragma unroll
      for (int ks = 0; ks < 8; ++ks) {
        const float4 p = *(const float4*)&partials[(size_t)ks * 524288 +
                                                   (size_t)b * 4096 + i * 4];
        s.x += p.x; s.y += p.y; s.z += p.z; s.w += p.w;
      }
    }
    ((float4*)o)[i] = s;
  }
}

// ---------------- GEMM v5: gload_lds 2-phase, split-K=8, NO atomics ---------
// grid 512 = 64 n-tiles x 8 k-splits; block 256 = 4 waves.
// A: bf16 [128][32] (8KB); B: f32 [64][32] (8KB); double-buffered.
// LDS linear for gload_lds; conflict-free via inverse-swizzled GLOBAL src.
// Epilogue: plain f32 stores to partials[ks][128][4096].
__global__ __launch_bounds__(256, 4) void gemm_v5(
    const unsigned short* __restrict__ xb, const float* __restrict__ w,
    float* __restrict__ partials) {
  __shared__ __align__(16) unsigned short A_lds[2][128 * 32];
  __shared__ __align__(16) float B_lds[2][64 * 32];
  const int tid = threadIdx.x, lane = tid & 63, wv = tid >> 6;
  const int fr = lane & 15, kq = lane >> 4;
  const int nt = blockIdx.x & 63, ks = blockIdx.x >> 6;
  const int n0 = nt * 64, k0 = ks * 512;

  const int sA0 = tid, sA1 = 256 + tid;
  const int rA0 = sA0 >> 2, cA0 = (sA0 & 3) ^ ((rA0 >> 1) & 3);
  const int rA1 = sA1 >> 2, cA1 = (sA1 & 3) ^ ((rA1 >> 1) & 3);
  const unsigned short* aSrc0 = xb + (size_t)rA0 * 4096 + k0 + cA0 * 8;
  const unsigned short* aSrc1 = xb + (size_t)rA1 * 4096 + k0 + cA1 * 8;
  const int rB0 = sA0 >> 3, cB0 = (sA0 & 7) ^ (rB0 & 7);
  const int rB1 = sA1 >> 3, cB1 = (sA1 & 7) ^ (rB1 & 7);
  const float* bSrc0 = w + (size_t)(n0 + rB0) * 4096 + k0 + cB0 * 4;
  const float* bSrc1 = w + (size_t)(n0 + rB1) * 4096 + k0 + cB1 * 4;

  f32x4 acc[8];
#pragma unroll
  for (int mi = 0; mi < 8; ++mi) acc[mi] = f32x4{0.f, 0.f, 0.f, 0.f};

  const int aslot = kq ^ ((fr >> 1) & 3);
  const int R2 = wv * 16 + fr;
  const int bo0 = R2 * 128 + (((kq * 2 + 0) ^ (R2 & 7)) * 16);
  const int bo1 = R2 * 128 + (((kq * 2 + 1) ^ (R2 & 7)) * 16);

  auto STAGE = [&](int buf, int t) {
    gload16(aSrc0 + t * 32, (char*)&A_lds[buf][0] + tid * 16);
    gload16(aSrc1 + t * 32, (char*)&A_lds[buf][0] + (256 + tid) * 16);
    gload16(bSrc0 + t * 32, (char*)&B_lds[buf][0] + tid * 16);
    gload16(bSrc1 + t * 32, (char*)&B_lds[buf][0] + (256 + tid) * 16);
  };

  STAGE(0, 0);
  __syncthreads();
  int cur = 0;
#pragma unroll
  for (int t = 0; t < 16; ++t) {
    if (t < 15) STAGE(cur ^ 1, t + 1);
    const char* Ab = (const char*)&A_lds[cur][0];
    const char* Bb = (const char*)&B_lds[cur][0];
    const float4 b0 = *(const float4*)(Bb + bo0);
    const float4 b1 = *(const float4*)(Bb + bo1);
    const bf16x8 bb = pack8(b0, b1);
#pragma unroll
    for (int mi = 0; mi < 8; ++mi) {
      const bf16x8 af = *(const bf16x8*)(Ab + (mi * 16 + fr) * 64 + aslot * 16);
      acc[mi] = __builtin_amdgcn_mfma_f32_16x16x32_bf16(af, bb, acc[mi], 0, 0, 0);
    }
    __syncthreads();
    cur ^= 1;
  }

  // C/D layout: col=lane&15, row=(lane>>4)*4+j  [m89-verified]
  float* P = partials + (size_t)ks * 524288;
  const int col = n0 + wv * 16 + fr;
  const int rq = kq * 4;
#pragma unroll
  for (int mi = 0; mi < 8; ++mi)
#pragma unroll
    for (int j = 0; j < 4; ++j)
      P[(size_t)(mi * 16 + rq + j) * 4096 + col] = acc[mi][j];
}

// ---------------- GEMM v4 (atomic fallback, ws >= 1MB only) -----------------
__global__ __launch_bounds__(256, 4) void gemm_v4(
    const unsigned short* __restrict__ xb, const float* __restrict__ w,
    float* __restrict__ out) {
  __shared__ __align__(16) unsigned short A_lds[2][128 * 32];
  __shared__ __align__(16) float B_lds[2][64 * 32];
  const int tid = threadIdx.x, lane = tid & 63, wv = tid >> 6;
  const int fr = lane & 15, kq = lane >> 4;
  const int nt = blockIdx.x & 63, ks = blockIdx.x >> 6;
  const int n0 = nt * 64, k0 = ks * 256;

  const int sA0 = tid, sA1 = 256 + tid;
  const int rA0 = sA0 >> 2, cA0 = (sA0 & 3) ^ ((rA0 >> 1) & 3);
  const int rA1 = sA1 >> 2, cA1 = (sA1 & 3) ^ ((rA1 >> 1) & 3);
  const unsigned short* aSrc0 = xb + (size_t)rA0 * 4096 + k0 + cA0 * 8;
  const unsigned short* aSrc1 = xb + (size_t)rA1 * 4096 + k0 + cA1 * 8;
  const int rB0 = sA0 >> 3, cB0 = (sA0 & 7) ^ (rB0 & 7);
  const int rB1 = sA1 >> 3, cB1 = (sA1 & 7) ^ (rB1 & 7);
  const float* bSrc0 = w + (size_t)(n0 + rB0) * 4096 + k0 + cB0 * 4;
  const float* bSrc1 = w + (size_t)(n0 + rB1) * 4096 + k0 + cB1 * 4;

  f32x4 acc[8];
#pragma unroll
  for (int mi = 0; mi < 8; ++mi) acc[mi] = f32x4{0.f, 0.f, 0.f, 0.f};

  const int aslot = kq ^ ((fr >> 1) & 3);
  const int R2 = wv * 16 + fr;
  const int bo0 = R2 * 128 + (((kq * 2 + 0) ^ (R2 & 7)) * 16);
  const int bo1 = R2 * 128 + (((kq * 2 + 1) ^ (R2 & 7)) * 16);

  auto STAGE = [&](int buf, int t) {
    gload16(aSrc0 + t * 32, (char*)&A_lds[buf][0] + tid * 16);
    gload16(aSrc1 + t * 32, (char*)&A_lds[buf][0] + (256 + tid) * 16);
    gload16(bSrc0 + t * 32, (char*)&B_lds[buf][0] + tid * 16);
    gload16(bSrc1 + t * 32, (char*)&B_lds[buf][0] + (256 + tid) * 16);
  };

  STAGE(0, 0);
  __syncthreads();
  int cur = 0;
#pragma unroll
  for (int t = 0; t < 8; ++t) {
    if (t < 7) STAGE(cur ^ 1, t + 1);
    const char* Ab = (const char*)&A_lds[cur][0];
    const char* Bb = (const char*)&B_lds[cur][0];
    const float4 b0 = *(const float4*)(Bb + bo0);
    const float4 b1 = *(const float4*)(Bb + bo1);
    const bf16x8 bb = pack8(b0, b1);
#pragma unroll
    for (int mi = 0; mi < 8; ++mi) {
      const bf16x8 af = *(const bf16x8*)(Ab + (mi * 16 + fr) * 64 + aslot * 16);
      acc[mi] = __builtin_amdgcn_mfma_f32_16x16x32_bf16(af, bb, acc[mi], 0, 0, 0);
    }
    __syncthreads();
    cur ^= 1;
  }

  const int col = n0 + wv * 16 + fr;
  const int rq = kq * 4;
#pragma unroll
  for (int mi = 0; mi < 8; ++mi)
#pragma unroll
    for (int j = 0; j < 4; ++j)
      atomicAdd(&out[(size_t)(mi * 16 + rq + j) * 4096 + col], acc[mi][j]);
}

// ---------------- GEMM fallback (round-1, no ws) ----------------------------
__global__ __launch_bounds__(256, 2) void gemm_kernel(
    const float* __restrict__ x, const float* __restrict__ w,
    float* __restrict__ out) {
  __shared__ __align__(16) unsigned short Asm[2][128][40];
  __shared__ __align__(16) unsigned short Bsm[2][64][40];
  const int tid = threadIdx.x;
  const int nt = blockIdx.x & 63, ks = blockIdx.x >> 6;
  const int n0 = nt * 64, k0 = ks * 512;
  const int q = tid & 7, r0 = tid >> 3;
  const int lane = tid & 63, wid = tid >> 6;
  const int wm = wid >> 1, wn = wid & 1;
  const int fr = lane & 15, k8 = (lane >> 4) * 8;

  f32x4 acc[4][2];
#pragma unroll
  for (int mi = 0; mi < 4; ++mi)
#pragma unroll
    for (int ni = 0; ni < 2; ++ni) acc[mi][ni] = f32x4{0.f, 0.f, 0.f, 0.f};

  float4 ra[4]; float4 rb[2];
#pragma unroll
  for (int p = 0; p < 4; ++p)
    ra[p] = *(const float4*)&x[(size_t)(r0 + p * 32) * 4096 + k0 + q * 4];
#pragma unroll
  for (int p = 0; p < 2; ++p)
    rb[p] = *(const float4*)&w[(size_t)(n0 + r0 + p * 32) * 4096 + k0 + q * 4];
#pragma unroll
  for (int p = 0; p < 4; ++p) {
    ushort4 pk = {f2bf(ra[p].x), f2bf(ra[p].y), f2bf(ra[p].z), f2bf(ra[p].w)};
    *(ushort4*)&Asm[0][r0 + p * 32][q * 4] = pk;
  }
#pragma unroll
  for (int p = 0; p < 2; ++p) {
    ushort4 pk = {f2bf(rb[p].x), f2bf(rb[p].y), f2bf(rb[p].z), f2bf(rb[p].w)};
    *(ushort4*)&Bsm[0][r0 + p * 32][q * 4] = pk;
  }
  __syncthreads();

  for (int t = 0; t < 16; ++t) {
    const int cb = t & 1;
    if (t < 15) {
      const int kg = k0 + (t + 1) * 32;
#pragma unroll
      for (int p = 0; p < 4; ++p)
        ra[p] = *(const float4*)&x[(size_t)(r0 + p * 32) * 4096 + kg + q * 4];
#pragma unroll
      for (int p = 0; p < 2; ++p)
        rb[p] = *(const float4*)&w[(size_t)(n0 + r0 + p * 32) * 4096 + kg + q * 4];
    }
    bf16x8 af[4], bg[2];
#pragma unroll
    for (int mi = 0; mi < 4; ++mi)
      af[mi] = *(const bf16x8*)&Asm[cb][wm * 64 + mi * 16 + fr][k8];
#pragma unroll
    for (int ni = 0; ni < 2; ++ni)
      bg[ni] = *(const bf16x8*)&Bsm[cb][wn * 32 + ni * 16 + fr][k8];
#pragma unroll
    for (int mi = 0; mi < 4; ++mi)
#pragma unroll
      for (int ni = 0; ni < 2; ++ni)
        acc[mi][ni] = __builtin_amdgcn_mfma_f32_16x16x32_bf16(af[mi], bg[ni],
                                                              acc[mi][ni], 0, 0, 0);
    if (t < 15) {
#pragma unroll
      for (int p = 0; p < 4; ++p) {
        ushort4 pk = {f2bf(ra[p].x), f2bf(ra[p].y), f2bf(ra[p].z), f2bf(ra[p].w)};
        *(ushort4*)&Asm[cb ^ 1][r0 + p * 32][q * 4] = pk;
      }
#pragma unroll
      for (int p = 0; p < 2; ++p) {
        ushort4 pk = {f2bf(rb[p].x), f2bf(rb[p].y), f2bf(rb[p].z), f2bf(rb[p].w)};
        *(ushort4*)&Bsm[cb ^ 1][r0 + p * 32][q * 4] = pk;
      }
    }
    __syncthreads();
  }

  const int rbase = wm * 64 + (lane >> 4) * 4;
  const int cbase = n0 + wn * 32 + fr;
#pragma unroll
  for (int mi = 0; mi < 4; ++mi)
#pragma unroll
    for (int ni = 0; ni < 2; ++ni)
#pragma unroll
      for (int j = 0; j < 4; ++j)
        atomicAdd(&out[(size_t)(rbase + mi * 16 + j) * 4096 + cbase + ni * 16],
                  acc[mi][ni][j]);
}

extern "C" void kernel_launch(void* const* d_in, const int* in_sizes, int n_in,
                              void* d_out, int out_size, void* d_ws, size_t ws_size,
                              hipStream_t stream) {
  const float* x    = (const float*)d_in[0];
  const float* w    = (const float*)d_in[1];
  const float* bias = (const float*)d_in[2];
  const float* scl  = (const float*)d_in[3];
  float* out = (float*)d_out;
  unsigned short* xbp = (unsigned short*)d_ws;
  float* partials = (float*)((char*)d_ws + (1 << 20));
  const size_t needFull = (1u << 20) + 8u * 524288u * 4u;   // 1MB xb + 16MB partials
  const bool fullWs = ws_size >= needFull;
  const bool miniWs = ws_size >= (size_t)128 * 4096 * 2;

  if (fullWs) {
    hipLaunchKernelGGL(cvt_x, dim3(512), dim3(256), 0, stream, x, xbp);
    hipLaunchKernelGGL(gemm_v5, dim3(512), dim3(256), 0, stream, xbp, w, partials);
    hipLaunchKernelGGL(wavelet_kernel, dim3(128), dim3(512), 0, stream,
                       x, bias, scl, out, xbp, partials, 0, 1);
  } else if (miniWs) {
    hipLaunchKernelGGL(wavelet_kernel, dim3(128), dim3(512), 0, stream,
                       x, bias, scl, out, xbp, (const float*)nullptr, 1, 0);
    hipLaunchKernelGGL(gemm_v4, dim3(1024), dim3(256), 0, stream, xbp, w, out);
  } else {
    hipLaunchKernelGGL(wavelet_kernel, dim3(128), dim3(512), 0, stream,
                       x, bias, scl, out, xbp, (const float*)nullptr, 0, 0);
    hipLaunchKernelGGL(gemm_kernel, dim3(512), dim3(256), 0, stream, x, w, out);
  }
}

// Round 6
// 126.401 us; speedup vs baseline: 1.2298x; 1.0107x over previous
//
#include <hip/hip_runtime.h>
#include <hip/hip_bf16.h>

typedef __attribute__((ext_vector_type(8))) short bf16x8;
typedef __attribute__((ext_vector_type(4))) float f32x4;

__device__ __forceinline__ unsigned short f2bf(float f) {
  unsigned int u = __float_as_uint(f);
  u += 0x7FFFu + ((u >> 16) & 1u);   // RTNE
  return (unsigned short)(u >> 16);
}

__device__ __forceinline__ bf16x8 pack8(float4 lo, float4 hi) {
  union { unsigned int u[4]; bf16x8 v; } r;
  asm("v_cvt_pk_bf16_f32 %0, %1, %2" : "=v"(r.u[0]) : "v"(lo.x), "v"(lo.y));
  asm("v_cvt_pk_bf16_f32 %0, %1, %2" : "=v"(r.u[1]) : "v"(lo.z), "v"(lo.w));
  asm("v_cvt_pk_bf16_f32 %0, %1, %2" : "=v"(r.u[2]) : "v"(hi.x), "v"(hi.y));
  asm("v_cvt_pk_bf16_f32 %0, %1, %2" : "=v"(r.u[3]) : "v"(hi.z), "v"(hi.w));
  return r.v;
}

__device__ __forceinline__ void gload16(const void* g, void* l) {
  __builtin_amdgcn_global_load_lds(
      (const __attribute__((address_space(1))) void*)g,
      (__attribute__((address_space(3))) void*)l, 16, 0, 0);
}

__host__ __device__ constexpr int prOffset(int l) {
  return (l == 0) ? 0 : (l == 1) ? 3072 : (l == 2) ? 3840 : 4032;
}

// ---------------- x -> bf16 (ws) --------------------------------------------
__global__ __launch_bounds__(256) void cvt_x(const float* __restrict__ x,
                                             unsigned short* __restrict__ xb) {
  const int i = blockIdx.x * 256 + threadIdx.x;          // 131072 float4s
  const float4 v = ((const float4*)x)[i];
  ushort4 pk = {f2bf(v.x), f2bf(v.y), f2bf(v.z), f2bf(v.w)};
  ((ushort4*)xb)[i] = pk;
}

// ---------------- wavelet level (512 threads, padded ab, b128 scans) --------
template<int L>
__device__ __forceinline__ void level_fwd(float* cur, float* tmp, float* ab,
                                          float* pr, float* thrL, float* thrH,
                                          const float* __restrict__ scl, int tid) {
  constexpr int HALF = 32 >> L, LOG2 = 5 - L, HH = HALF * HALF, TOT = 4 * HH;
  constexpr int H = HALF * 2;
  constexpr int ST = HALF + 4;                 // padded stride (16B-aligned)
  constexpr float P = 0.4f * (float)(HALF - 1);
  constexpr int K = (int)P;
  constexpr float FRAC = P - (float)K;
  const float s0 = scl[4 * L + 0], s1 = scl[4 * L + 1];
  const float s2 = scl[4 * L + 2], s3 = scl[4 * L + 3];
  // DWT (raw) -> tmp; fused scaled-abs -> padded ab
  for (int e = tid; e < HH; e += 512) {
    const int i = e >> LOG2, j = e & (HALF - 1);
    const float a = cur[(i * 2) * H + j * 2];
    const float b = cur[(i * 2) * H + j * 2 + 1];
    const float c = cur[(i * 2 + 1) * H + j * 2];
    const float d = cur[(i * 2 + 1) * H + j * 2 + 1];
    const float vA = (((a + b) + c) + d) * 0.5f;
    const float vH = (((a - b) + c) - d) * 0.5f;
    const float vV = (((a + b) - c) - d) * 0.5f;
    const float vD = (((a - b) - c) + d) * 0.5f;
    tmp[e]          = vA;  ab[(0 * HALF + i) * ST + j] = fabsf(vA * s0);
    tmp[HH + e]     = vH;  ab[(1 * HALF + i) * ST + j] = fabsf(vH * s1);
    tmp[2 * HH + e] = vV;  ab[(2 * HALF + i) * ST + j] = fabsf(vV * s2);
    tmp[3 * HH + e] = vD;  ab[(3 * HALF + i) * ST + j] = fabsf(vD * s3);
  }
  __syncthreads();
  // counting selection: ranks K and K+1 per row; row scan via float4 chunks
  constexpr int CH = (TOT >= 512) ? TOT / 512 : 1;
  {
    const int base = tid * CH;
    if (base < TOT) {
      const int row = base >> LOG2;
      const int c0 = base & (HALF - 1);
      const float* rp = &ab[row * ST];
      float v[CH]; int clt[CH], ceq[CH];
#pragma unroll
      for (int c = 0; c < CH; ++c) { v[c] = rp[c0 + c]; clt[c] = 0; ceq[c] = 0; }
#pragma unroll
      for (int rq = 0; rq < HALF / 4; ++rq) {
        const float4 q = *(const float4*)&rp[rq * 4];
        float qa[4] = {q.x, q.y, q.z, q.w};
#pragma unroll
        for (int z = 0; z < 4; ++z) {
#pragma unroll
          for (int c = 0; c < CH; ++c) {
            clt[c] += (qa[z] < v[c]) ? 1 : 0;
            ceq[c] += (qa[z] == v[c]) ? 1 : 0;
          }
        }
      }
#pragma unroll
      for (int c = 0; c < CH; ++c) {
        if (clt[c] <= K && K < clt[c] + ceq[c]) thrL[row] = v[c];
        if (clt[c] <= K + 1 && K + 1 < clt[c] + ceq[c]) thrH[row] = v[c];
      }
    }
  }
  __syncthreads();
  // prune + route (scaled H,V,D -> pr; raw cA -> cur; scaled cA at L==3)
  for (int e = tid; e < TOT; e += 512) {
    const int s = e >> (2 * LOG2);
    const int row = e >> LOG2;
    const float sc = (s < 2) ? (s == 0 ? s0 : s1) : (s == 2 ? s2 : s3);
    const float thr = thrL[row] * (1.0f - FRAC) + thrH[row] * FRAC;
    const float co = tmp[e] * sc;
    const float val = (fabsf(co) > thr) ? co : 0.0f;
    if (s >= 1) pr[prOffset(L) + e - HH] = val;
    else {
      if (L == 3) pr[4080 + e] = val;
      cur[e] = tmp[e];
    }
  }
  __syncthreads();
}

// full wavelet for one image; sh = 16384 floats (64 KB)
__device__ __forceinline__ void wavelet_block(
    float* sh, const float* __restrict__ x, const float* __restrict__ bias,
    const float* __restrict__ scl, float* __restrict__ out, int b, int tid) {
  float* cur = sh;
  float* tmp = sh + 4096;
  float* ab  = sh + 8192;   // L0 padded rows spill into pr[0..512) -- safe
  float* pr  = sh + 12288;
  float* thrL = cur + 2048;
  float* thrH = cur + 2176;
  const float* xi = x + (size_t)b * 4096;
  for (int i = tid; i < 1024; i += 512)
    *(float4*)&cur[i * 4] = ((const float4*)xi)[i];
  __syncthreads();

  level_fwd<0>(cur, tmp, ab, pr, thrL, thrH, scl, tid);
  level_fwd<1>(cur, tmp, ab, pr, thrL, thrH, scl, tid);
  level_fwd<2>(cur, tmp, ab, pr, thrL, thrH, scl, tid);
  level_fwd<3>(cur, tmp, ab, pr, thrL, thrH, scl, tid);

#pragma unroll
  for (int l = 3; l >= 0; --l) {
    const int half = 64 >> (l + 1);
    const int hh = half * half;
    const int po = prOffset(l);
    const float* src = (l == 3) ? &pr[4080] : ((l & 1) ? tmp : cur);
    float* dst = (l & 1) ? cur : tmp;
    const int W2 = half * 2;
    for (int e = tid; e < hh; e += 512) {
      const int i = e / half, j = e - i * half;
      const float cA = src[e];
      const float cH = pr[po + 0 * hh + i * half + j];
      const float cV = pr[po + 1 * hh + i * half + j];
      const float cD = pr[po + 2 * hh + i * half + j];
      const float a2 = (((cA + cH) + cV) + cD) * 0.5f;
      const float b2 = (((cA - cH) + cV) - cD) * 0.5f;
      const float c2 = (((cA + cH) - cV) - cD) * 0.5f;
      const float d2 = (((cA - cH) - cV) + cD) * 0.5f;
      dst[(i * 2) * W2 + j * 2]         = a2;
      dst[(i * 2) * W2 + j * 2 + 1]     = b2;
      dst[(i * 2 + 1) * W2 + j * 2]     = c2;
      dst[(i * 2 + 1) * W2 + j * 2 + 1] = d2;
    }
    __syncthreads();
  }
  float* o = out + (size_t)b * 4096;
  const float4* t4 = (const float4*)tmp;
  const float4* b4 = (const float4*)bias;
  for (int i = tid; i < 1024; i += 512) {
    float4 t = t4[i], bb = b4[i];
    float4 r = {t.x + bb.x, t.y + bb.y, t.z + bb.z, t.w + bb.w};
    ((float4*)o)[i] = r;
  }
}

// gemm role: 512 thr / 8 waves, BN=64, split-K=4 (K-chunk 1024, 32 steps).
// A bf16 [128][32] via gload_lds (slot swz kq^((r>>1)&3)); B f32 [64][32]
// (slot swz c^(r&7)); both bank-uniform on b128 reads. Partials: plain stores.
__device__ __forceinline__ void gemm_block(
    char* smem, int gb, const unsigned short* __restrict__ xb,
    const float* __restrict__ w, float* __restrict__ partials) {
  unsigned short* Abuf = (unsigned short*)smem;          // [2][4096] bf16
  char* Bbuf = smem + 16384;                             // [2][2048] f32
  const int tid = threadIdx.x, lane = tid & 63, wv = tid >> 6;
  const int fr = lane & 15, kq = lane >> 4;
  const int nt = gb & 63, ks = gb >> 6;
  const int n0 = nt * 64, k0 = ks * 1024;

  const int ra = tid >> 2, ca = (tid & 3) ^ ((ra >> 1) & 3);
  const unsigned short* aSrc = xb + (size_t)ra * 4096 + k0 + ca * 8;
  const int rb = tid >> 3, cb = (tid & 7) ^ (rb & 7);
  const float* bSrc = w + (size_t)(n0 + rb) * 4096 + k0 + cb * 4;
  char* aDst = (char*)Abuf + tid * 16;
  char* bDst = Bbuf + tid * 16;

  const int asw = (fr >> 1) & 3, bsw = fr & 7;
  const int RB = (wv & 3) * 16 + fr;
  const int bo0 = RB * 128 + (((2 * kq) ^ bsw) << 4);
  const int bo1 = RB * 128 + (((2 * kq + 1) ^ bsw) << 4);
  const int aoBase = ((wv >> 2) * 64 + fr) * 64 + ((kq ^ asw) << 4);

  f32x4 acc[4];
#pragma unroll
  for (int mi = 0; mi < 4; ++mi) acc[mi] = f32x4{0.f, 0.f, 0.f, 0.f};

  auto STAGE = [&](int buf, int t) {
    gload16(aSrc + t * 32, aDst + buf * 8192);
    gload16(bSrc + t * 32, bDst + buf * 8192);
  };

  STAGE(0, 0);
  __syncthreads();
  for (int t = 0; t < 32; ++t) {
    const int cur = t & 1;
    if (t < 31) STAGE(cur ^ 1, t + 1);
    const char* A = (const char*)Abuf + cur * 8192;
    const char* B = Bbuf + cur * 8192;
    const float4 b0 = *(const float4*)(B + bo0);
    const float4 b1 = *(const float4*)(B + bo1);
    const bf16x8 bbv = pack8(b0, b1);
#pragma unroll
    for (int mi = 0; mi < 4; ++mi) {
      const bf16x8 af = *(const bf16x8*)(A + aoBase + mi * 1024);  // 16 rows * 64B
      acc[mi] = __builtin_amdgcn_mfma_f32_16x16x32_bf16(af, bbv, acc[mi], 0, 0, 0);
    }
    __syncthreads();
  }

  // C/D: col=lane&15, row=(lane>>4)*4+j  [m89-verified]
  float* P = partials + (size_t)ks * 524288;
  const int col = n0 + (wv & 3) * 16 + fr;
  const int r0 = (wv >> 2) * 64 + kq * 4;
#pragma unroll
  for (int mi = 0; mi < 4; ++mi)
#pragma unroll
    for (int j = 0; j < 4; ++j)
      P[(size_t)(r0 + mi * 16 + j) * 4096 + col] = acc[mi][j];
}

// ---------------- fused: blocks 0-127 wavelet, 128-383 gemm -----------------
__global__ __launch_bounds__(512, 4) void fused_kernel(
    const float* __restrict__ x, const float* __restrict__ bias,
    const float* __restrict__ scl, float* __restrict__ out,
    const unsigned short* __restrict__ xb, const float* __restrict__ w,
    float* __restrict__ partials) {
  __shared__ __align__(16) float sh[16384];              // 64 KB
  if (blockIdx.x < 128)
    wavelet_block(sh, x, bias, scl, out, blockIdx.x, threadIdx.x);
  else
    gemm_block((char*)sh, blockIdx.x - 128, xb, w, partials);
}

// ---------------- reduce: out += sum of 4 partials --------------------------
__global__ __launch_bounds__(256) void reduce_k(float* __restrict__ out,
                                                const float* __restrict__ partials) {
  const int i = blockIdx.x * 256 + threadIdx.x;          // 131072 float4s
  float4 o = ((float4*)out)[i];
#pragma unroll
  for (int ks = 0; ks < 4; ++ks) {
    const float4 p = ((const float4*)(partials + (size_t)ks * 524288))[i];
    o.x += p.x; o.y += p.y; o.z += p.z; o.w += p.w;
  }
  ((float4*)out)[i] = o;
}

// ---------------- fallbacks (small ws) --------------------------------------
__global__ __launch_bounds__(512) void wavelet_only(
    const float* __restrict__ x, const float* __restrict__ bias,
    const float* __restrict__ scl, float* __restrict__ out) {
  __shared__ __align__(16) float sh[16384];
  wavelet_block(sh, x, bias, scl, out, blockIdx.x, threadIdx.x);
}

__global__ __launch_bounds__(256, 2) void gemm_kernel(
    const float* __restrict__ x, const float* __restrict__ w,
    float* __restrict__ out) {
  __shared__ __align__(16) unsigned short Asm[2][128][40];
  __shared__ __align__(16) unsigned short Bsm[2][64][40];
  const int tid = threadIdx.x;
  const int nt = blockIdx.x & 63, ks = blockIdx.x >> 6;
  const int n0 = nt * 64, k0 = ks * 512;
  const int q = tid & 7, r0 = tid >> 3;
  const int lane = tid & 63, wid = tid >> 6;
  const int wm = wid >> 1, wn = wid & 1;
  const int fr = lane & 15, k8 = (lane >> 4) * 8;

  f32x4 acc[4][2];
#pragma unroll
  for (int mi = 0; mi < 4; ++mi)
#pragma unroll
    for (int ni = 0; ni < 2; ++ni) acc[mi][ni] = f32x4{0.f, 0.f, 0.f, 0.f};

  float4 ra[4]; float4 rb[2];
#pragma unroll
  for (int p = 0; p < 4; ++p)
    ra[p] = *(const float4*)&x[(size_t)(r0 + p * 32) * 4096 + k0 + q * 4];
#pragma unroll
  for (int p = 0; p < 2; ++p)
    rb[p] = *(const float4*)&w[(size_t)(n0 + r0 + p * 32) * 4096 + k0 + q * 4];
#pragma unroll
  for (int p = 0; p < 4; ++p) {
    ushort4 pk = {f2bf(ra[p].x), f2bf(ra[p].y), f2bf(ra[p].z), f2bf(ra[p].w)};
    *(ushort4*)&Asm[0][r0 + p * 32][q * 4] = pk;
  }
#pragma unroll
  for (int p = 0; p < 2; ++p) {
    ushort4 pk = {f2bf(rb[p].x), f2bf(rb[p].y), f2bf(rb[p].z), f2bf(rb[p].w)};
    *(ushort4*)&Bsm[0][r0 + p * 32][q * 4] = pk;
  }
  __syncthreads();

  for (int t = 0; t < 16; ++t) {
    const int cb2 = t & 1;
    if (t < 15) {
      const int kg = k0 + (t + 1) * 32;
#pragma unroll
      for (int p = 0; p < 4; ++p)
        ra[p] = *(const float4*)&x[(size_t)(r0 + p * 32) * 4096 + kg + q * 4];
#pragma unroll
      for (int p = 0; p < 2; ++p)
        rb[p] = *(const float4*)&w[(size_t)(n0 + r0 + p * 32) * 4096 + kg + q * 4];
    }
    bf16x8 af[4], bg[2];
#pragma unroll
    for (int mi = 0; mi < 4; ++mi)
      af[mi] = *(const bf16x8*)&Asm[cb2][wm * 64 + mi * 16 + fr][k8];
#pragma unroll
    for (int ni = 0; ni < 2; ++ni)
      bg[ni] = *(const bf16x8*)&Bsm[cb2][wn * 32 + ni * 16 + fr][k8];
#pragma unroll
    for (int mi = 0; mi < 4; ++mi)
#pragma unroll
      for (int ni = 0; ni < 2; ++ni)
        acc[mi][ni] = __builtin_amdgcn_mfma_f32_16x16x32_bf16(af[mi], bg[ni],
                                                              acc[mi][ni], 0, 0, 0);
    if (t < 15) {
#pragma unroll
      for (int p = 0; p < 4; ++p) {
        ushort4 pk = {f2bf(ra[p].x), f2bf(ra[p].y), f2bf(ra[p].z), f2bf(ra[p].w)};
        *(ushort4*)&Asm[cb2 ^ 1][r0 + p * 32][q * 4] = pk;
      }
#pragma unroll
      for (int p = 0; p < 2; ++p) {
        ushort4 pk = {f2bf(rb[p].x), f2bf(rb[p].y), f2bf(rb[p].z), f2bf(rb[p].w)};
        *(ushort4*)&Bsm[cb2 ^ 1][r0 + p * 32][q * 4] = pk;
      }
    }
    __syncthreads();
  }

  const int rbase = wm * 64 + (lane >> 4) * 4;
  const int cbase = n0 + wn * 32 + fr;
#pragma unroll
  for (int mi = 0; mi < 4; ++mi)
#pragma unroll
    for (int ni = 0; ni < 2; ++ni)
#pragma unroll
      for (int j = 0; j < 4; ++j)
        atomicAdd(&out[(size_t)(rbase + mi * 16 + j) * 4096 + cbase + ni * 16],
                  acc[mi][ni][j]);
}

extern "C" void kernel_launch(void* const* d_in, const int* in_sizes, int n_in,
                              void* d_out, int out_size, void* d_ws, size_t ws_size,
                              hipStream_t stream) {
  const float* x    = (const float*)d_in[0];
  const float* w    = (const float*)d_in[1];
  const float* bias = (const float*)d_in[2];
  const float* scl  = (const float*)d_in[3];
  float* out = (float*)d_out;
  unsigned short* xbp = (unsigned short*)d_ws;
  float* partials = (float*)((char*)d_ws + (1 << 20));
  const size_t need = (1u << 20) + 4u * 524288u * 4u;     // 1MB xb + 8MB partials
  if (ws_size >= need) {
    hipLaunchKernelGGL(cvt_x, dim3(512), dim3(256), 0, stream, x, xbp);
    hipLaunchKernelGGL(fused_kernel, dim3(384), dim3(512), 0, stream,
                       x, bias, scl, out, xbp, w, partials);
    hipLaunchKernelGGL(reduce_k, dim3(512), dim3(256), 0, stream, out, partials);
  } else {
    hipLaunchKernelGGL(wavelet_only, dim3(128), dim3(512), 0, stream,
                       x, bias, scl, out);
    hipLaunchKernelGGL(gemm_kernel, dim3(512), dim3(256), 0, stream, x, w, out);
  }
}

// Round 7
// 126.046 us; speedup vs baseline: 1.2333x; 1.0028x over previous
//
#include <hip/hip_runtime.h>
#include <hip/hip_bf16.h>

typedef __attribute__((ext_vector_type(8))) short bf16x8;
typedef __attribute__((ext_vector_type(4))) float f32x4;

__device__ __forceinline__ unsigned short f2bf(float f) {
  unsigned int u = __float_as_uint(f);
  u += 0x7FFFu + ((u >> 16) & 1u);   // RTNE
  return (unsigned short)(u >> 16);
}

__device__ __forceinline__ bf16x8 pack8(float4 lo, float4 hi) {
  union { unsigned int u[4]; bf16x8 v; } r;
  asm("v_cvt_pk_bf16_f32 %0, %1, %2" : "=v"(r.u[0]) : "v"(lo.x), "v"(lo.y));
  asm("v_cvt_pk_bf16_f32 %0, %1, %2" : "=v"(r.u[1]) : "v"(lo.z), "v"(lo.w));
  asm("v_cvt_pk_bf16_f32 %0, %1, %2" : "=v"(r.u[2]) : "v"(hi.x), "v"(hi.y));
  asm("v_cvt_pk_bf16_f32 %0, %1, %2" : "=v"(r.u[3]) : "v"(hi.z), "v"(hi.w));
  return r.v;
}

__device__ __forceinline__ void gload16(const void* g, void* l) {
  __builtin_amdgcn_global_load_lds(
      (const __attribute__((address_space(1))) void*)g,
      (__attribute__((address_space(3))) void*)l, 16, 0, 0);
}

__host__ __device__ constexpr int prOffset(int l) {
  return (l == 0) ? 0 : (l == 1) ? 3072 : (l == 2) ? 3840 : 4032;
}

// ---------------- x -> bf16 (ws) --------------------------------------------
__global__ __launch_bounds__(256) void cvt_x(const float* __restrict__ x,
                                             unsigned short* __restrict__ xb) {
  const int i = blockIdx.x * 256 + threadIdx.x;          // 131072 float4s
  const float4 v = ((const float4*)x)[i];
  ushort4 pk = {f2bf(v.x), f2bf(v.y), f2bf(v.z), f2bf(v.w)};
  ((ushort4*)xb)[i] = pk;
}

// ---------------- wavelet level (1024 threads, padded ab, b128 scans) -------
template<int L>
__device__ __forceinline__ void level_fwd(float* cur, float* tmp, float* ab,
                                          float* pr, float* thrL, float* thrH,
                                          const float* __restrict__ scl, int tid) {
  constexpr int HALF = 32 >> L, LOG2 = 5 - L, HH = HALF * HALF, TOT = 4 * HH;
  constexpr int H = HALF * 2;
  constexpr int ST = HALF + 4;                 // padded stride (16B-aligned rows)
  constexpr float P = 0.4f * (float)(HALF - 1);
  constexpr int K = (int)P;
  constexpr float FRAC = P - (float)K;
  const float s0 = scl[4 * L + 0], s1 = scl[4 * L + 1];
  const float s2 = scl[4 * L + 2], s3 = scl[4 * L + 3];
  // DWT (raw) -> tmp; fused scaled-abs -> padded ab
  for (int e = tid; e < HH; e += 1024) {
    const int i = e >> LOG2, j = e & (HALF - 1);
    const float a = cur[(i * 2) * H + j * 2];
    const float b = cur[(i * 2) * H + j * 2 + 1];
    const float c = cur[(i * 2 + 1) * H + j * 2];
    const float d = cur[(i * 2 + 1) * H + j * 2 + 1];
    const float vA = (((a + b) + c) + d) * 0.5f;
    const float vH = (((a - b) + c) - d) * 0.5f;
    const float vV = (((a + b) - c) - d) * 0.5f;
    const float vD = (((a - b) - c) + d) * 0.5f;
    tmp[e]          = vA;  ab[(0 * HALF + i) * ST + j] = fabsf(vA * s0);
    tmp[HH + e]     = vH;  ab[(1 * HALF + i) * ST + j] = fabsf(vH * s1);
    tmp[2 * HH + e] = vV;  ab[(2 * HALF + i) * ST + j] = fabsf(vV * s2);
    tmp[3 * HH + e] = vD;  ab[(3 * HALF + i) * ST + j] = fabsf(vD * s3);
  }
  __syncthreads();
  // counting selection: ranks K,K+1 per row; row scan via float4 (padded banks)
  constexpr int CH = (TOT >= 1024) ? TOT / 1024 : 1;
  {
    const int base = tid * CH;
    if (base < TOT) {
      const int row = base >> LOG2;
      const int c0 = base & (HALF - 1);
      const float* rp = &ab[row * ST];
      float v[CH]; int clt[CH], ceq[CH];
#pragma unroll
      for (int c = 0; c < CH; ++c) { v[c] = rp[c0 + c]; clt[c] = 0; ceq[c] = 0; }
#pragma unroll
      for (int rq = 0; rq < HALF / 4; ++rq) {
        const float4 q = *(const float4*)&rp[rq * 4];
        float qa[4] = {q.x, q.y, q.z, q.w};
#pragma unroll
        for (int z = 0; z < 4; ++z) {
#pragma unroll
          for (int c = 0; c < CH; ++c) {
            clt[c] += (qa[z] < v[c]) ? 1 : 0;
            ceq[c] += (qa[z] == v[c]) ? 1 : 0;
          }
        }
      }
#pragma unroll
      for (int c = 0; c < CH; ++c) {
        if (clt[c] <= K && K < clt[c] + ceq[c]) thrL[row] = v[c];
        if (clt[c] <= K + 1 && K + 1 < clt[c] + ceq[c]) thrH[row] = v[c];
      }
    }
  }
  __syncthreads();
  // prune + route (scaled H,V,D -> pr; raw cA -> cur; scaled cA at L==3)
  for (int e = tid; e < TOT; e += 1024) {
    const int s = e >> (2 * LOG2);
    const int row = e >> LOG2;
    const float sc = (s < 2) ? (s == 0 ? s0 : s1) : (s == 2 ? s2 : s3);
    const float thr = thrL[row] * (1.0f - FRAC) + thrH[row] * FRAC;
    const float co = tmp[e] * sc;
    const float val = (fabsf(co) > thr) ? co : 0.0f;
    if (s >= 1) pr[prOffset(L) + e - HH] = val;
    else {
      if (L == 3) pr[4080 + e] = val;
      cur[e] = tmp[e];
    }
  }
  __syncthreads();
}

// One block per image, 1024 threads. out = wavelet + bias (+ sum of partials).
__global__ __launch_bounds__(1024) void wavelet_kernel(
    const float* __restrict__ x, const float* __restrict__ bias,
    const float* __restrict__ scl, float* __restrict__ out,
    const float* __restrict__ partials, int addPartials) {
  __shared__ __align__(16) float sh[16384];    // 64 KB: cur|tmp|ab|pr
  float* cur = sh;
  float* tmp = sh + 4096;
  float* ab  = sh + 8192;   // L0 padded rows spill into pr[0..512) -- safe
  float* pr  = sh + 12288;
  float* thrL = cur + 2048;                    // dead region of cur
  float* thrH = cur + 2176;
  const int b = blockIdx.x, tid = threadIdx.x;
  const float* xi = x + (size_t)b * 4096;

  for (int i = tid; i < 1024; i += 1024)
    *(float4*)&cur[i * 4] = ((const float4*)xi)[i];
  __syncthreads();

  level_fwd<0>(cur, tmp, ab, pr, thrL, thrH, scl, tid);
  level_fwd<1>(cur, tmp, ab, pr, thrL, thrH, scl, tid);
  level_fwd<2>(cur, tmp, ab, pr, thrL, thrH, scl, tid);
  level_fwd<3>(cur, tmp, ab, pr, thrL, thrH, scl, tid);

#pragma unroll
  for (int l = 3; l >= 0; --l) {
    const int half = 64 >> (l + 1);
    const int hh = half * half;
    const int po = prOffset(l);
    const float* src = (l == 3) ? &pr[4080] : ((l & 1) ? tmp : cur);
    float* dst = (l & 1) ? cur : tmp;
    const int W2 = half * 2;
    for (int e = tid; e < hh; e += 1024) {
      const int i = e / half, j = e - i * half;
      const float cA = src[e];
      const float cH = pr[po + 0 * hh + i * half + j];
      const float cV = pr[po + 1 * hh + i * half + j];
      const float cD = pr[po + 2 * hh + i * half + j];
      const float a2 = (((cA + cH) + cV) + cD) * 0.5f;
      const float b2 = (((cA - cH) + cV) - cD) * 0.5f;
      const float c2 = (((cA + cH) - cV) - cD) * 0.5f;
      const float d2 = (((cA - cH) - cV) + cD) * 0.5f;
      dst[(i * 2) * W2 + j * 2]         = a2;
      dst[(i * 2) * W2 + j * 2 + 1]     = b2;
      dst[(i * 2 + 1) * W2 + j * 2]     = c2;
      dst[(i * 2 + 1) * W2 + j * 2 + 1] = d2;
    }
    __syncthreads();
  }
  // epilogue: out = wavelet + bias (+ sum of 8 split-K GEMM partials)
  float* o = out + (size_t)b * 4096;
  const float4* t4 = (const float4*)tmp;
  const float4* b4 = (const float4*)bias;
  for (int i = tid; i < 1024; i += 1024) {
    float4 t = t4[i], bb = b4[i];
    float4 s = {t.x + bb.x, t.y + bb.y, t.z + bb.z, t.w + bb.w};
    if (addPartials) {
#pragma unroll
      for (int ks = 0; ks < 8; ++ks) {
        const float4 p = *(const float4*)&partials[(size_t)ks * 524288 +
                                                   (size_t)b * 4096 + i * 4];
        s.x += p.x; s.y += p.y; s.z += p.z; s.w += p.w;
      }
    }
    ((float4*)o)[i] = s;
  }
}

// ---------------- GEMM v5: gload_lds 2-phase, split-K=8, partial stores -----
// grid 512 = 64 n-tiles x 8 k-splits; block 256 = 4 waves. (round-5 proven)
__global__ __launch_bounds__(256, 4) void gemm_v5(
    const unsigned short* __restrict__ xb, const float* __restrict__ w,
    float* __restrict__ partials) {
  __shared__ __align__(16) unsigned short A_lds[2][128 * 32];
  __shared__ __align__(16) float B_lds[2][64 * 32];
  const int tid = threadIdx.x, lane = tid & 63, wv = tid >> 6;
  const int fr = lane & 15, kq = lane >> 4;
  const int nt = blockIdx.x & 63, ks = blockIdx.x >> 6;
  const int n0 = nt * 64, k0 = ks * 512;

  const int sA0 = tid, sA1 = 256 + tid;
  const int rA0 = sA0 >> 2, cA0 = (sA0 & 3) ^ ((rA0 >> 1) & 3);
  const int rA1 = sA1 >> 2, cA1 = (sA1 & 3) ^ ((rA1 >> 1) & 3);
  const unsigned short* aSrc0 = xb + (size_t)rA0 * 4096 + k0 + cA0 * 8;
  const unsigned short* aSrc1 = xb + (size_t)rA1 * 4096 + k0 + cA1 * 8;
  const int rB0 = sA0 >> 3, cB0 = (sA0 & 7) ^ (rB0 & 7);
  const int rB1 = sA1 >> 3, cB1 = (sA1 & 7) ^ (rB1 & 7);
  const float* bSrc0 = w + (size_t)(n0 + rB0) * 4096 + k0 + cB0 * 4;
  const float* bSrc1 = w + (size_t)(n0 + rB1) * 4096 + k0 + cB1 * 4;

  f32x4 acc[8];
#pragma unroll
  for (int mi = 0; mi < 8; ++mi) acc[mi] = f32x4{0.f, 0.f, 0.f, 0.f};

  const int aslot = kq ^ ((fr >> 1) & 3);
  const int R2 = wv * 16 + fr;
  const int bo0 = R2 * 128 + (((kq * 2 + 0) ^ (R2 & 7)) * 16);
  const int bo1 = R2 * 128 + (((kq * 2 + 1) ^ (R2 & 7)) * 16);

  auto STAGE = [&](int buf, int t) {
    gload16(aSrc0 + t * 32, (char*)&A_lds[buf][0] + tid * 16);
    gload16(aSrc1 + t * 32, (char*)&A_lds[buf][0] + (256 + tid) * 16);
    gload16(bSrc0 + t * 32, (char*)&B_lds[buf][0] + tid * 16);
    gload16(bSrc1 + t * 32, (char*)&B_lds[buf][0] + (256 + tid) * 16);
  };

  STAGE(0, 0);
  __syncthreads();
  int cur = 0;
#pragma unroll
  for (int t = 0; t < 16; ++t) {
    if (t < 15) STAGE(cur ^ 1, t + 1);
    const char* Ab = (const char*)&A_lds[cur][0];
    const char* Bb = (const char*)&B_lds[cur][0];
    const float4 b0 = *(const float4*)(Bb + bo0);
    const float4 b1 = *(const float4*)(Bb + bo1);
    const bf16x8 bb = pack8(b0, b1);
#pragma unroll
    for (int mi = 0; mi < 8; ++mi) {
      const bf16x8 af = *(const bf16x8*)(Ab + (mi * 16 + fr) * 64 + aslot * 16);
      acc[mi] = __builtin_amdgcn_mfma_f32_16x16x32_bf16(af, bb, acc[mi], 0, 0, 0);
    }
    __syncthreads();
    cur ^= 1;
  }

  // C/D layout: col=lane&15, row=(lane>>4)*4+j  [m89-verified]
  float* P = partials + (size_t)ks * 524288;
  const int col = n0 + wv * 16 + fr;
  const int rq = kq * 4;
#pragma unroll
  for (int mi = 0; mi < 8; ++mi)
#pragma unroll
    for (int j = 0; j < 4; ++j)
      P[(size_t)(mi * 16 + rq + j) * 4096 + col] = acc[mi][j];
}

// ---------------- fallback (no/small ws): round-1 style ---------------------
__global__ __launch_bounds__(256, 2) void gemm_kernel(
    const float* __restrict__ x, const float* __restrict__ w,
    float* __restrict__ out) {
  __shared__ __align__(16) unsigned short Asm[2][128][40];
  __shared__ __align__(16) unsigned short Bsm[2][64][40];
  const int tid = threadIdx.x;
  const int nt = blockIdx.x & 63, ks = blockIdx.x >> 6;
  const int n0 = nt * 64, k0 = ks * 512;
  const int q = tid & 7, r0 = tid >> 3;
  const int lane = tid & 63, wid = tid >> 6;
  const int wm = wid >> 1, wn = wid & 1;
  const int fr = lane & 15, k8 = (lane >> 4) * 8;

  f32x4 acc[4][2];
#pragma unroll
  for (int mi = 0; mi < 4; ++mi)
#pragma unroll
    for (int ni = 0; ni < 2; ++ni) acc[mi][ni] = f32x4{0.f, 0.f, 0.f, 0.f};

  float4 ra[4]; float4 rb[2];
#pragma unroll
  for (int p = 0; p < 4; ++p)
    ra[p] = *(const float4*)&x[(size_t)(r0 + p * 32) * 4096 + k0 + q * 4];
#pragma unroll
  for (int p = 0; p < 2; ++p)
    rb[p] = *(const float4*)&w[(size_t)(n0 + r0 + p * 32) * 4096 + k0 + q * 4];
#pragma unroll
  for (int p = 0; p < 4; ++p) {
    ushort4 pk = {f2bf(ra[p].x), f2bf(ra[p].y), f2bf(ra[p].z), f2bf(ra[p].w)};
    *(ushort4*)&Asm[0][r0 + p * 32][q * 4] = pk;
  }
#pragma unroll
  for (int p = 0; p < 2; ++p) {
    ushort4 pk = {f2bf(rb[p].x), f2bf(rb[p].y), f2bf(rb[p].z), f2bf(rb[p].w)};
    *(ushort4*)&Bsm[0][r0 + p * 32][q * 4] = pk;
  }
  __syncthreads();

  for (int t = 0; t < 16; ++t) {
    const int cb2 = t & 1;
    if (t < 15) {
      const int kg = k0 + (t + 1) * 32;
#pragma unroll
      for (int p = 0; p < 4; ++p)
        ra[p] = *(const float4*)&x[(size_t)(r0 + p * 32) * 4096 + kg + q * 4];
#pragma unroll
      for (int p = 0; p < 2; ++p)
        rb[p] = *(const float4*)&w[(size_t)(n0 + r0 + p * 32) * 4096 + kg + q * 4];
    }
    bf16x8 af[4], bg[2];
#pragma unroll
    for (int mi = 0; mi < 4; ++mi)
      af[mi] = *(const bf16x8*)&Asm[cb2][wm * 64 + mi * 16 + fr][k8];
#pragma unroll
    for (int ni = 0; ni < 2; ++ni)
      bg[ni] = *(const bf16x8*)&Bsm[cb2][wn * 32 + ni * 16 + fr][k8];
#pragma unroll
    for (int mi = 0; mi < 4; ++mi)
#pragma unroll
      for (int ni = 0; ni < 2; ++ni)
        acc[mi][ni] = __builtin_amdgcn_mfma_f32_16x16x32_bf16(af[mi], bg[ni],
                                                              acc[mi][ni], 0, 0, 0);
    if (t < 15) {
#pragma unroll
      for (int p = 0; p < 4; ++p) {
        ushort4 pk = {f2bf(ra[p].x), f2bf(ra[p].y), f2bf(ra[p].z), f2bf(ra[p].w)};
        *(ushort4*)&Asm[cb2 ^ 1][r0 + p * 32][q * 4] = pk;
      }
#pragma unroll
      for (int p = 0; p < 2; ++p) {
        ushort4 pk = {f2bf(rb[p].x), f2bf(rb[p].y), f2bf(rb[p].z), f2bf(rb[p].w)};
        *(ushort4*)&Bsm[cb2 ^ 1][r0 + p * 32][q * 4] = pk;
      }
    }
    __syncthreads();
  }

  const int rbase = wm * 64 + (lane >> 4) * 4;
  const int cbase = n0 + wn * 32 + fr;
#pragma unroll
  for (int mi = 0; mi < 4; ++mi)
#pragma unroll
    for (int ni = 0; ni < 2; ++ni)
#pragma unroll
      for (int j = 0; j < 4; ++j)
        atomicAdd(&out[(size_t)(rbase + mi * 16 + j) * 4096 + cbase + ni * 16],
                  acc[mi][ni][j]);
}

extern "C" void kernel_launch(void* const* d_in, const int* in_sizes, int n_in,
                              void* d_out, int out_size, void* d_ws, size_t ws_size,
                              hipStream_t stream) {
  const float* x    = (const float*)d_in[0];
  const float* w    = (const float*)d_in[1];
  const float* bias = (const float*)d_in[2];
  const float* scl  = (const float*)d_in[3];
  float* out = (float*)d_out;
  unsigned short* xbp = (unsigned short*)d_ws;
  float* partials = (float*)((char*)d_ws + (1 << 20));
  const size_t need = (1u << 20) + 8u * 524288u * 4u;     // 1MB xb + 16MB partials
  if (ws_size >= need) {
    hipLaunchKernelGGL(cvt_x, dim3(512), dim3(256), 0, stream, x, xbp);
    hipLaunchKernelGGL(gemm_v5, dim3(512), dim3(256), 0, stream, xbp, w, partials);
    hipLaunchKernelGGL(wavelet_kernel, dim3(128), dim3(1024), 0, stream,
                       x, bias, scl, out, partials, 1);
  } else {
    hipLaunchKernelGGL(wavelet_kernel, dim3(128), dim3(1024), 0, stream,
                       x, bias, scl, out, (const float*)nullptr, 0);
    hipLaunchKernelGGL(gemm_kernel, dim3(512), dim3(256), 0, stream, x, w, out);
  }
}